// Round 3
// baseline (5912.699 us; speedup 1.0000x reference)
//
#include <hip/hip_runtime.h>
#include <hip/hip_bf16.h>

#define BN_EPS 1e-5f

// ---------------- canonicalize edge_index (handles int32 or int64 storage) ----------------
// int64 little-endian: element j = words [2j](low) [2j+1](high); indices < 2^31 -> high word 0.
__global__ void k_canon(const int* __restrict__ ei, int* __restrict__ src32,
                        int* __restrict__ dst32, int E) {
    __shared__ int is64;
    if (threadIdx.x == 0) {
        int any = 0;
        for (int j = 1; j < 512; j += 2) any |= ei[j];
        is64 = (any == 0);
    }
    __syncthreads();
    int e = blockIdx.x * blockDim.x + threadIdx.x;
    if (e < E) {
        if (is64) { src32[e] = ei[2 * e]; dst32[e] = ei[2 * E + 2 * e]; }
        else      { src32[e] = ei[e];     dst32[e] = ei[E + e]; }
    }
}

// ---------------- degree / dinv / edge norm ----------------
__global__ void k_deg_init(float* deg, int N) {
    int i = blockIdx.x * blockDim.x + threadIdx.x;
    if (i < N) deg[i] = 1.0f;  // self-loop weight
}

__global__ void k_deg_edges(const int* __restrict__ dst32, const float* __restrict__ w,
                            float* deg, int E) {
    int e = blockIdx.x * blockDim.x + threadIdx.x;
    if (e < E) atomicAdd(&deg[dst32[e]], w[e]);
}

__global__ void k_dinv(float* deg, int N) {
    int i = blockIdx.x * blockDim.x + threadIdx.x;
    if (i < N) deg[i] = rsqrtf(deg[i]);  // deg >= 1 always
}

__global__ void k_norm(const int* __restrict__ src32, const int* __restrict__ dst32,
                       const float* __restrict__ w, const float* __restrict__ dinv,
                       float* __restrict__ nrm, int E) {
    int e = blockIdx.x * blockDim.x + threadIdx.x;
    if (e < E) nrm[e] = dinv[src32[e]] * w[e] * dinv[dst32[e]];
}

// ---------------- dense transform: out[N][128] = in[N][K] @ W[K][128] ----------------
// f32 in/out. In-place safe (each block reads+writes only its own rows).
template <int K>
__global__ void k_mm(const float* __restrict__ inp, const float* __restrict__ W,
                     float* __restrict__ out, int N) {
    const int M = 16;  // rows per block
    __shared__ float tile[M][K];
    const int c = threadIdx.x;  // 0..127 output col
    const int r0 = blockIdx.x * M;
    for (int idx = threadIdx.x; idx < M * K; idx += 128) {
        int r = idx / K, k = idx % K;
        int row = r0 + r;
        tile[r][k] = (row < N) ? inp[(size_t)row * K + k] : 0.f;
    }
    __syncthreads();
    float acc[M];
#pragma unroll
    for (int r = 0; r < M; ++r) acc[r] = 0.f;
    for (int k = 0; k < K; ++k) {
        float wv = W[k * 128 + c];  // L2-resident
#pragma unroll
        for (int r = 0; r < M; ++r) acc[r] += tile[r][k] * wv;
    }
    __syncthreads();  // for in-place use
#pragma unroll
    for (int r = 0; r < M; ++r) {
        int row = r0 + r;
        if (row < N) out[(size_t)row * 128 + c] = acc[r];
    }
}

// ---------------- aggregation ----------------
// agg[n][c] = dinv[n]^2 * h[n][c] + b[c]   (self-loop + bias)
__global__ void k_agg_init(const float* __restrict__ h, const float* __restrict__ dinv,
                           const float* __restrict__ b, float* __restrict__ agg, int N) {
    int i = blockIdx.x * blockDim.x + threadIdx.x;  // N*32 lanes, float4 each
    if (i >= N * 32) return;
    int n = i >> 5, q = i & 31, c0 = q * 4;
    float di = dinv[n];
    float s = di * di;
    float4 hv = ((const float4*)h)[(size_t)n * 32 + q];
    float4 o;
    o.x = s * hv.x + b[c0 + 0];
    o.y = s * hv.y + b[c0 + 1];
    o.z = s * hv.z + b[c0 + 2];
    o.w = s * hv.w + b[c0 + 3];
    ((float4*)agg)[(size_t)n * 32 + q] = o;
}

// agg[dst][c] += norm[e] * h[src][c]
__global__ void k_agg_edges(const int* __restrict__ src32, const int* __restrict__ dst32,
                            const float* __restrict__ nrm, const float* __restrict__ h,
                            float* __restrict__ agg, int E) {
    long long i = (long long)blockIdx.x * blockDim.x + threadIdx.x;  // E*32 lanes
    if (i >= (long long)E * 32) return;
    int e = (int)(i >> 5), q = (int)(i & 31);
    int s = src32[e], d = dst32[e];
    float w = nrm[e];
    float4 hv = ((const float4*)h)[(size_t)s * 32 + q];
    float* op = agg + (size_t)d * 128 + q * 4;
    atomicAdd(op + 0, w * hv.x);
    atomicAdd(op + 1, w * hv.y);
    atomicAdd(op + 2, w * hv.z);
    atomicAdd(op + 3, w * hv.w);
}

// ---------------- batchnorm ----------------
// stats[c] = sum, stats[128+c] = sumsq  (pre-zeroed)
__global__ void k_bn_stats(const float* __restrict__ h, float* __restrict__ stats, int N) {
    int c = threadIdx.x & 127;
    int rowStart = blockIdx.x * 2 + (threadIdx.x >> 7);
    int rowStride = gridDim.x * 2;
    float s = 0.f, q = 0.f;
    for (int n = rowStart; n < N; n += rowStride) {
        float v = h[(size_t)n * 128 + c];
        s += v;
        q += v * v;
    }
    atomicAdd(&stats[c], s);
    atomicAdd(&stats[128 + c], q);
}

__global__ void k_bn_relu(const float* __restrict__ in, const float* __restrict__ stats,
                          const float* __restrict__ g, const float* __restrict__ be,
                          float* __restrict__ out, int N) {
    int i = blockIdx.x * blockDim.x + threadIdx.x;  // N*32 lanes
    if (i >= N * 32) return;
    int n = i >> 5, q = i & 31, c0 = q * 4;
    float invN = 1.0f / (float)N;
    float4 v = ((const float4*)in)[(size_t)n * 32 + q];
    float vv[4] = {v.x, v.y, v.z, v.w};
    float o[4];
#pragma unroll
    for (int j = 0; j < 4; ++j) {
        int c = c0 + j;
        float mean = stats[c] * invN;
        float var = stats[128 + c] * invN - mean * mean;
        float scale = g[c] * rsqrtf(var + BN_EPS);
        float shift = be[c] - mean * scale;
        o[j] = fmaxf(0.f, vv[j] * scale + shift);
    }
    float4 ov = {o[0], o[1], o[2], o[3]};
    ((float4*)out)[(size_t)n * 32 + q] = ov;
}

// ---------------- fused head: BN2+ReLU, feature concat, @ Wm + bm ----------------
__global__ void k_final(const float* __restrict__ hagg, const float* __restrict__ stats,
                        const float* __restrict__ g2, const float* __restrict__ be2,
                        const float* __restrict__ dist, const float* __restrict__ degf,
                        const float* __restrict__ Wd, const float* __restrict__ bd,
                        const float* __restrict__ Wg, const float* __restrict__ bg,
                        const float* __restrict__ Wm, const float* __restrict__ bm,
                        float* __restrict__ out, int N) {
    const int M = 16;
    __shared__ float tile[M][384];
    __shared__ float sc[128], sh[128];
    const int c = threadIdx.x;  // 128 threads
    const int r0 = blockIdx.x * M;

    {  // per-channel BN params
        float invN = 1.0f / (float)N;
        float mean = stats[c] * invN;
        float var = stats[128 + c] * invN - mean * mean;
        float scale = g2[c] * rsqrtf(var + BN_EPS);
        sc[c] = scale;
        sh[c] = be2[c] - mean * scale;
    }
    __syncthreads();

    for (int idx = threadIdx.x; idx < M * 128; idx += 128) {
        int r = idx >> 7, cc = idx & 127;
        int row = r0 + r;
        float h2 = 0.f, dv = 0.f, gv = 0.f;
        if (row < N) {
            h2 = fmaxf(0.f, hagg[(size_t)row * 128 + cc] * sc[cc] + sh[cc]);
            dv = fmaxf(0.f, dist[row] * Wd[cc] + bd[cc]);
            gv = fmaxf(0.f, degf[row] * Wg[cc] + bg[cc]);
        }
        tile[r][cc] = h2;
        tile[r][128 + cc] = dv;
        tile[r][256 + cc] = gv;
    }
    __syncthreads();

    float acc[M];
#pragma unroll
    for (int r = 0; r < M; ++r) acc[r] = 0.f;
    for (int k = 0; k < 384; ++k) {
        float wv = Wm[k * 128 + c];
#pragma unroll
        for (int r = 0; r < M; ++r) acc[r] += tile[r][k] * wv;
    }
    float bias = bm[c];
#pragma unroll
    for (int r = 0; r < M; ++r) {
        int row = r0 + r;
        if (row < N) out[(size_t)row * 128 + c] = acc[r] + bias;
    }
}

extern "C" void kernel_launch(void* const* d_in, const int* in_sizes, int n_in,
                              void* d_out, int out_size, void* d_ws, size_t ws_size,
                              hipStream_t stream) {
    const float* x    = (const float*)d_in[0];
    const int*   ei   = (const int*)d_in[1];
    const float* ew   = (const float*)d_in[2];
    const float* dist = (const float*)d_in[3];
    const float* degf = (const float*)d_in[4];
    const float* W1   = (const float*)d_in[5];
    const float* b1   = (const float*)d_in[6];
    const float* W2   = (const float*)d_in[7];
    const float* b2   = (const float*)d_in[8];
    const float* g1   = (const float*)d_in[9];
    const float* be1  = (const float*)d_in[10];
    const float* g2   = (const float*)d_in[11];
    const float* be2  = (const float*)d_in[12];
    const float* Wd   = (const float*)d_in[13];
    const float* bd   = (const float*)d_in[14];
    const float* Wg   = (const float*)d_in[15];
    const float* bg   = (const float*)d_in[16];
    const float* Wm   = (const float*)d_in[17];
    const float* bm   = (const float*)d_in[18];

    const int IN = 64;
    const int N = in_sizes[0] / IN;   // 100000
    const int E = in_sizes[1] / 2;    // 1600000

    // ws layout (bytes): src32[E] | dst32[E] | norm[E] | dinv[N] | stats[512] | agg[N*128]
    int*   src32 = (int*)d_ws;
    int*   dst32 = src32 + E;
    float* nrm   = (float*)(dst32 + E);
    float* dinv  = nrm + E;
    float* stats = dinv + N;
    float* agg   = stats + 512;
    float* hbuf  = (float*)d_out;   // f32 staging; fully overwritten by k_final

    hipMemsetAsync(stats, 0, 512 * sizeof(float), stream);

    const int nbE1 = (E + 255) / 256;
    k_canon<<<nbE1, 256, 0, stream>>>(ei, src32, dst32, E);
    k_deg_init<<<(N + 255) / 256, 256, 0, stream>>>(dinv, N);
    k_deg_edges<<<nbE1, 256, 0, stream>>>(dst32, ew, dinv, E);
    k_dinv<<<(N + 255) / 256, 256, 0, stream>>>(dinv, N);
    k_norm<<<nbE1, 256, 0, stream>>>(src32, dst32, ew, dinv, nrm, E);

    const int nb16 = (N + 15) / 16;
    const int nb32 = (N * 32 + 255) / 256;
    const long long tE = (long long)E * 32;
    const int nbE = (int)((tE + 255) / 256);

    // layer 1: x @ W1 -> hbuf; aggregate -> agg; BN+ReLU -> hbuf
    k_mm<64><<<nb16, 128, 0, stream>>>(x, W1, hbuf, N);
    k_agg_init<<<nb32, 256, 0, stream>>>(hbuf, dinv, b1, agg, N);
    k_agg_edges<<<nbE, 256, 0, stream>>>(src32, dst32, nrm, hbuf, agg, E);
    k_bn_stats<<<512, 256, 0, stream>>>(agg, stats, N);
    k_bn_relu<<<nb32, 256, 0, stream>>>(agg, stats, g1, be1, hbuf, N);

    // layer 2: hbuf @ W2 -> hbuf (in-place safe); aggregate -> agg
    k_mm<128><<<nb16, 128, 0, stream>>>(hbuf, W2, hbuf, N);
    k_agg_init<<<nb32, 256, 0, stream>>>(hbuf, dinv, b2, agg, N);
    k_agg_edges<<<nbE, 256, 0, stream>>>(src32, dst32, nrm, hbuf, agg, E);
    k_bn_stats<<<512, 256, 0, stream>>>(agg, stats + 256, N);

    // fused BN2+ReLU + concat + head matmul -> d_out
    k_final<<<nb16, 128, 0, stream>>>(agg, stats + 256, g2, be2, dist, degf,
                                      Wd, bd, Wg, bg, Wm, bm, (float*)d_out, N);
}

// Round 4
// 1062.691 us; speedup vs baseline: 5.5639x; 5.5639x over previous
//
#include <hip/hip_runtime.h>
#include <hip/hip_bf16.h>

#define BN_EPS 1e-5f

// ---------------- canonicalize edge_index (+ dst histogram + weighted degree) ----------------
// int64 little-endian: element j = words [2j](low) [2j+1](high); indices < 2^31 -> high word 0.
__global__ void k_canon_hist(const int* __restrict__ ei, const float* __restrict__ ew,
                             int* __restrict__ src32, int* __restrict__ dst32,
                             int* __restrict__ cnt, float* __restrict__ deg, int E) {
    __shared__ int is64;
    if (threadIdx.x == 0) {
        int any = 0;
        for (int j = 1; j < 512; j += 2) any |= ei[j];
        is64 = (any == 0);
    }
    __syncthreads();
    int e = blockIdx.x * blockDim.x + threadIdx.x;
    if (e < E) {
        int s, d;
        if (is64) { s = ei[2 * e]; d = ei[2 * E + 2 * e]; }
        else      { s = ei[e];     d = ei[E + e]; }
        src32[e] = s;
        dst32[e] = d;
        atomicAdd(&cnt[d], 1);
        atomicAdd(&deg[d], ew[e]);
    }
}

__global__ void k_dinv(float* deg, int N) {
    int i = blockIdx.x * blockDim.x + threadIdx.x;
    if (i < N) deg[i] = rsqrtf(deg[i] + 1.0f);  // +1 = self-loop
}

// ---------------- exclusive scan of cnt[N] -> rowptr[N] (1024 elems / block) ----------------
__global__ void k_scan1(const int* __restrict__ cnt, int* __restrict__ rowptr,
                        int* __restrict__ blktot, int N) {
    __shared__ int lds[256];
    int tid = threadIdx.x;
    int base = blockIdx.x * 1024 + tid * 4;
    int v[4]; int s = 0;
#pragma unroll
    for (int j = 0; j < 4; ++j) { v[j] = (base + j < N) ? cnt[base + j] : 0; s += v[j]; }
    lds[tid] = s;
    __syncthreads();
    for (int off = 1; off < 256; off <<= 1) {
        int t = (tid >= off) ? lds[tid - off] : 0;
        __syncthreads();
        lds[tid] += t;
        __syncthreads();
    }
    if (tid == 255) blktot[blockIdx.x] = lds[255];
    int run = lds[tid] - s;  // exclusive prefix of this thread's chunk within block
#pragma unroll
    for (int j = 0; j < 4; ++j) {
        if (base + j < N) rowptr[base + j] = run;
        run += v[j];
    }
}

__global__ void k_scan2(int* blktot, int nb) {  // single block, nb <= 256
    __shared__ int lds[256];
    int tid = threadIdx.x;
    int v = (tid < nb) ? blktot[tid] : 0;
    lds[tid] = v;
    __syncthreads();
    for (int off = 1; off < 256; off <<= 1) {
        int t = (tid >= off) ? lds[tid - off] : 0;
        __syncthreads();
        lds[tid] += t;
        __syncthreads();
    }
    if (tid < nb) blktot[tid] = lds[tid] - v;  // exclusive
}

__global__ void k_scan3(int* __restrict__ rowptr, const int* __restrict__ blktot,
                        int* __restrict__ cur, int N) {
    int i = blockIdx.x * blockDim.x + threadIdx.x;
    if (i < N) {
        int v = rowptr[i] + blktot[i >> 10];
        rowptr[i] = v;
        cur[i] = v;
    }
}

// ---------------- scatter edges into CSR (cur advances to row end) ----------------
__global__ void k_scatter(const int* __restrict__ src32, const int* __restrict__ dst32,
                          const float* __restrict__ ew, const float* __restrict__ dinv,
                          int* __restrict__ cur, int* __restrict__ esrc,
                          float* __restrict__ enorm, int E) {
    int e = blockIdx.x * blockDim.x + threadIdx.x;
    if (e < E) {
        int s = src32[e], d = dst32[e];
        int pos = atomicAdd(&cur[d], 1);
        esrc[pos] = s;
        enorm[pos] = dinv[s] * ew[e] * dinv[d];
    }
}

// ---------------- dense transform: out[N][128] = in[N][K] @ W[K][128] ----------------
// Optional fused BN+ReLU applied to the INPUT while loading (BN params from stats).
template <int K, bool BN>
__global__ void k_mm(const float* __restrict__ inp, const float* __restrict__ W,
                     const float* __restrict__ stats, const float* __restrict__ g,
                     const float* __restrict__ be, float* __restrict__ out,
                     int N, float invN) {
    const int M = 16;
    __shared__ float tile[M][K];
    __shared__ float sc[K], sh[K];
    const int c = threadIdx.x;  // 0..127
    const int r0 = blockIdx.x * M;
    if (BN) {
        for (int k = threadIdx.x; k < K; k += 128) {
            float mean = stats[k] * invN;
            float var = stats[K + k] * invN - mean * mean;
            float scale = g[k] * rsqrtf(var + BN_EPS);
            sc[k] = scale;
            sh[k] = be[k] - mean * scale;
        }
        __syncthreads();
    }
    for (int idx = threadIdx.x; idx < M * K; idx += 128) {
        int r = idx / K, k = idx % K;
        int row = r0 + r;
        float v = (row < N) ? inp[(size_t)row * K + k] : 0.f;
        if (BN) v = fmaxf(0.f, v * sc[k] + sh[k]);
        tile[r][k] = v;
    }
    __syncthreads();
    float acc[M];
#pragma unroll
    for (int r = 0; r < M; ++r) acc[r] = 0.f;
    for (int k = 0; k < K; ++k) {
        float wv = W[k * 128 + c];
#pragma unroll
        for (int r = 0; r < M; ++r) acc[r] += tile[r][k] * wv;
    }
#pragma unroll
    for (int r = 0; r < M; ++r) {
        int row = r0 + r;
        if (row < N) out[(size_t)row * 128 + c] = acc[r];
    }
}

// ---------------- CSR gather aggregation (no atomics) ----------------
// agg[n][c] = dinv[n]^2 * h[n][c] + b[c] + sum_{j in row n} enorm[j] * h[esrc[j]][c]
__global__ void k_gather(const float* __restrict__ h, const int* __restrict__ esrc,
                         const float* __restrict__ enorm, const int* __restrict__ rowptr,
                         const int* __restrict__ rowend, const float* __restrict__ dinv,
                         const float* __restrict__ bias, float* __restrict__ agg, int N) {
    int node = blockIdx.x * 4 + (threadIdx.x >> 6);  // one wave per node
    int lane = threadIdx.x & 63;
    if (node >= N) return;
    int start = rowptr[node], end = rowend[node];
    float di = dinv[node];
    float sl = di * di;
    float2 hv = ((const float2*)(h + (size_t)node * 128))[lane];
    float2 bv = ((const float2*)bias)[lane];
    float ax = sl * hv.x + bv.x;
    float ay = sl * hv.y + bv.y;
    for (int j = start; j < end; ++j) {
        int s = esrc[j];
        float w = enorm[j];
        float2 v = ((const float2*)(h + (size_t)s * 128))[lane];
        ax += w * v.x;
        ay += w * v.y;
    }
    float2 o = {ax, ay};
    ((float2*)(agg + (size_t)node * 128))[lane] = o;
}

// ---------------- batchnorm stats ----------------
__global__ void k_bn_stats(const float* __restrict__ h, float* __restrict__ stats, int N) {
    int c = threadIdx.x & 127;
    int rowStart = blockIdx.x * 2 + (threadIdx.x >> 7);
    int rowStride = gridDim.x * 2;
    float s = 0.f, q = 0.f;
    for (int n = rowStart; n < N; n += rowStride) {
        float v = h[(size_t)n * 128 + c];
        s += v;
        q += v * v;
    }
    atomicAdd(&stats[c], s);
    atomicAdd(&stats[128 + c], q);
}

// ---------------- fused head: BN2+ReLU, feature concat, @ Wm + bm ----------------
__global__ void k_final(const float* __restrict__ hagg, const float* __restrict__ stats,
                        const float* __restrict__ g2, const float* __restrict__ be2,
                        const float* __restrict__ dist, const float* __restrict__ degf,
                        const float* __restrict__ Wd, const float* __restrict__ bd,
                        const float* __restrict__ Wg, const float* __restrict__ bg,
                        const float* __restrict__ Wm, const float* __restrict__ bm,
                        float* __restrict__ out, int N) {
    const int M = 16;
    __shared__ float tile[M][384];
    __shared__ float sc[128], sh[128];
    const int c = threadIdx.x;  // 128 threads
    const int r0 = blockIdx.x * M;

    {
        float invN = 1.0f / (float)N;
        float mean = stats[c] * invN;
        float var = stats[128 + c] * invN - mean * mean;
        float scale = g2[c] * rsqrtf(var + BN_EPS);
        sc[c] = scale;
        sh[c] = be2[c] - mean * scale;
    }
    __syncthreads();

    for (int idx = threadIdx.x; idx < M * 128; idx += 128) {
        int r = idx >> 7, cc = idx & 127;
        int row = r0 + r;
        float h2 = 0.f, dv = 0.f, gv = 0.f;
        if (row < N) {
            h2 = fmaxf(0.f, hagg[(size_t)row * 128 + cc] * sc[cc] + sh[cc]);
            dv = fmaxf(0.f, dist[row] * Wd[cc] + bd[cc]);
            gv = fmaxf(0.f, degf[row] * Wg[cc] + bg[cc]);
        }
        tile[r][cc] = h2;
        tile[r][128 + cc] = dv;
        tile[r][256 + cc] = gv;
    }
    __syncthreads();

    float acc[M];
#pragma unroll
    for (int r = 0; r < M; ++r) acc[r] = 0.f;
    for (int k = 0; k < 384; ++k) {
        float wv = Wm[k * 128 + c];
#pragma unroll
        for (int r = 0; r < M; ++r) acc[r] += tile[r][k] * wv;
    }
    float bias = bm[c];
#pragma unroll
    for (int r = 0; r < M; ++r) {
        int row = r0 + r;
        if (row < N) out[(size_t)row * 128 + c] = acc[r] + bias;
    }
}

extern "C" void kernel_launch(void* const* d_in, const int* in_sizes, int n_in,
                              void* d_out, int out_size, void* d_ws, size_t ws_size,
                              hipStream_t stream) {
    const float* x    = (const float*)d_in[0];
    const int*   ei   = (const int*)d_in[1];
    const float* ew   = (const float*)d_in[2];
    const float* dist = (const float*)d_in[3];
    const float* degf = (const float*)d_in[4];
    const float* W1   = (const float*)d_in[5];
    const float* b1   = (const float*)d_in[6];
    const float* W2   = (const float*)d_in[7];
    const float* b2   = (const float*)d_in[8];
    const float* g1   = (const float*)d_in[9];
    const float* be1  = (const float*)d_in[10];
    const float* g2   = (const float*)d_in[11];
    const float* be2  = (const float*)d_in[12];
    const float* Wd   = (const float*)d_in[13];
    const float* bd   = (const float*)d_in[14];
    const float* Wg   = (const float*)d_in[15];
    const float* bg   = (const float*)d_in[16];
    const float* Wm   = (const float*)d_in[17];
    const float* bm   = (const float*)d_in[18];

    const int IN = 64;
    const int N = in_sizes[0] / IN;   // 100000
    const int E = in_sizes[1] / 2;    // 1600000

    // ws layout (4B units):
    // cnt[N] | deg[N] | stats[512] | rowptr[N] | cur[N] | src32[E] | dst32[E] |
    // esrc[E] | enorm[E] | blktot[256] | agg[N*128]     (~78.5 MB total)
    int*   cnt    = (int*)d_ws;
    float* deg    = (float*)(cnt + N);          // becomes dinv in-place
    float* stats  = deg + N;                    // [0:256) layer1, [256:512) layer2
    int*   rowptr = (int*)(stats + 512);
    int*   cur    = rowptr + N;
    int*   src32  = cur + N;
    int*   dst32  = src32 + E;
    int*   esrc   = dst32 + E;
    float* enorm  = (float*)(esrc + E);
    int*   blktot = (int*)(enorm + E);
    float* agg    = (float*)(blktot + 256);
    float* hbuf   = (float*)d_out;              // transform staging; overwritten by k_final
    float* dinv   = deg;

    // zero cnt, deg, stats in one shot (they are contiguous)
    hipMemsetAsync(cnt, 0, (size_t)(2 * N + 512) * sizeof(float), stream);

    const int nbE = (E + 255) / 256;
    const int nbN = (N + 255) / 256;
    const int nscan = (N + 1023) / 1024;   // <= 256

    k_canon_hist<<<nbE, 256, 0, stream>>>(ei, ew, src32, dst32, cnt, deg, E);
    k_dinv<<<nbN, 256, 0, stream>>>(deg, N);
    k_scan1<<<nscan, 256, 0, stream>>>(cnt, rowptr, blktot, N);
    k_scan2<<<1, 256, 0, stream>>>(blktot, nscan);
    k_scan3<<<nbN, 256, 0, stream>>>(rowptr, blktot, cur, N);
    k_scatter<<<nbE, 256, 0, stream>>>(src32, dst32, ew, dinv, cur, esrc, enorm, E);

    const int nb16 = (N + 15) / 16;
    const int nbG  = (N + 3) / 4;
    const float invN = 1.0f / (float)N;

    // layer 1: x @ W1 -> hbuf; CSR gather -> agg; stats
    k_mm<64, false><<<nb16, 128, 0, stream>>>(x, W1, nullptr, nullptr, nullptr, hbuf, N, invN);
    k_gather<<<nbG, 256, 0, stream>>>(hbuf, esrc, enorm, rowptr, cur, dinv, b1, agg, N);
    k_bn_stats<<<512, 256, 0, stream>>>(agg, stats, N);

    // layer 2: (BN1+ReLU fused) agg @ W2 -> hbuf; CSR gather -> agg; stats
    k_mm<128, true><<<nb16, 128, 0, stream>>>(agg, W2, stats, g1, be1, hbuf, N, invN);
    k_gather<<<nbG, 256, 0, stream>>>(hbuf, esrc, enorm, rowptr, cur, dinv, b2, agg, N);
    k_bn_stats<<<512, 256, 0, stream>>>(agg, stats + 256, N);

    // fused BN2+ReLU + concat + head matmul -> d_out
    k_final<<<nb16, 128, 0, stream>>>(agg, stats + 256, g2, be2, dist, degf,
                                      Wd, bd, Wg, bg, Wm, bm, (float*)d_out, N);
}

// Round 5
// 792.117 us; speedup vs baseline: 7.4644x; 1.3416x over previous
//
#include <hip/hip_runtime.h>
#include <hip/hip_bf16.h>

#define BN_EPS 1e-5f

typedef __attribute__((ext_vector_type(8))) short bf16x8;
typedef __attribute__((ext_vector_type(4))) float f32x4;

__device__ __forceinline__ short f2b(float f) {
    __hip_bfloat16 h = __float2bfloat16(f);
    return *reinterpret_cast<short*>(&h);
}

// ---------------- canonicalize edge_index (+ dst histogram + weighted degree) ----------------
__global__ void k_canon_hist(const int* __restrict__ ei, const float* __restrict__ ew,
                             int* __restrict__ src32, int* __restrict__ dst32,
                             int* __restrict__ cnt, float* __restrict__ deg, int E) {
    __shared__ int is64;
    if (threadIdx.x == 0) {
        int any = 0;
        for (int j = 1; j < 512; j += 2) any |= ei[j];
        is64 = (any == 0);
    }
    __syncthreads();
    int e = blockIdx.x * blockDim.x + threadIdx.x;
    if (e < E) {
        int s, d;
        if (is64) { s = ei[2 * e]; d = ei[2 * E + 2 * e]; }
        else      { s = ei[e];     d = ei[E + e]; }
        src32[e] = s;
        dst32[e] = d;
        atomicAdd(&cnt[d], 1);
        atomicAdd(&deg[d], ew[e]);
    }
}

__global__ void k_dinv(float* deg, int N) {
    int i = blockIdx.x * blockDim.x + threadIdx.x;
    if (i < N) deg[i] = rsqrtf(deg[i] + 1.0f);  // +1 = self-loop
}

// ---------------- exclusive scan of cnt[N] -> rowptr[N] ----------------
__global__ void k_scan1(const int* __restrict__ cnt, int* __restrict__ rowptr,
                        int* __restrict__ blktot, int N) {
    __shared__ int lds[256];
    int tid = threadIdx.x;
    int base = blockIdx.x * 1024 + tid * 4;
    int v[4]; int s = 0;
#pragma unroll
    for (int j = 0; j < 4; ++j) { v[j] = (base + j < N) ? cnt[base + j] : 0; s += v[j]; }
    lds[tid] = s;
    __syncthreads();
    for (int off = 1; off < 256; off <<= 1) {
        int t = (tid >= off) ? lds[tid - off] : 0;
        __syncthreads();
        lds[tid] += t;
        __syncthreads();
    }
    if (tid == 255) blktot[blockIdx.x] = lds[255];
    int run = lds[tid] - s;
#pragma unroll
    for (int j = 0; j < 4; ++j) {
        if (base + j < N) rowptr[base + j] = run;
        run += v[j];
    }
}

__global__ void k_scan2(int* blktot, int nb) {
    __shared__ int lds[256];
    int tid = threadIdx.x;
    int v = (tid < nb) ? blktot[tid] : 0;
    lds[tid] = v;
    __syncthreads();
    for (int off = 1; off < 256; off <<= 1) {
        int t = (tid >= off) ? lds[tid - off] : 0;
        __syncthreads();
        lds[tid] += t;
        __syncthreads();
    }
    if (tid < nb) blktot[tid] = lds[tid] - v;
}

__global__ void k_scan3(int* __restrict__ rowptr, const int* __restrict__ blktot,
                        int* __restrict__ cur, int N) {
    int i = blockIdx.x * blockDim.x + threadIdx.x;
    if (i < N) {
        int v = rowptr[i] + blktot[i >> 10];
        rowptr[i] = v;
        cur[i] = v;
    }
}

__global__ void k_scatter(const int* __restrict__ src32, const int* __restrict__ dst32,
                          const float* __restrict__ ew, const float* __restrict__ dinv,
                          int* __restrict__ cur, int* __restrict__ esrc,
                          float* __restrict__ enorm, int E) {
    int e = blockIdx.x * blockDim.x + threadIdx.x;
    if (e < E) {
        int s = src32[e], d = dst32[e];
        int pos = atomicAdd(&cur[d], 1);
        esrc[pos] = s;
        enorm[pos] = dinv[s] * ew[e] * dinv[d];
    }
}

// ---------------- pre-transpose weights to bf16: Wt[c][k] = W[k][c] ----------------
__global__ void k_prep_wt(const float* __restrict__ W1, const float* __restrict__ W2,
                          const float* __restrict__ Wm, short* __restrict__ w1t,
                          short* __restrict__ w2t, short* __restrict__ wmt) {
    int idx = blockIdx.x * 256 + threadIdx.x;
    if (idx < 128 * 64) {
        int c = idx >> 6, k = idx & 63;
        w1t[idx] = f2b(W1[k * 128 + c]);
    } else if (idx < 128 * 64 + 128 * 128) {
        int i = idx - 128 * 64; int c = i >> 7, k = i & 127;
        w2t[i] = f2b(W2[k * 128 + c]);
    } else if (idx < 128 * 64 + 128 * 128 + 128 * 384) {
        int i = idx - (128 * 64 + 128 * 128); int c = i / 384, k = i % 384;
        wmt[i] = f2b(Wm[k * 128 + c]);
    }
}

// ---------------- MFMA GEMM: out[N][128] = stageA(A)[N][K] @ Bt^T + (bias) ----------------
// MODE 0: A plain f32 [N][K].
// MODE 1: A = agg [N][128]; BN(stats,g,be)+ReLU fused on load.
// MODE 2: K=384 virtual: k<128 BN2+ReLU(agg); 128..255 relu(dist*Wd+bd); 256..383 relu(degf*Wg+bg);
//         bias bm added in epilogue.
template <int K, int MODE>
__global__ __launch_bounds__(256) void k_gemm(
        const float* __restrict__ A, const short* __restrict__ Bt,
        const float* __restrict__ stats, const float* __restrict__ g,
        const float* __restrict__ be, const float* __restrict__ dist,
        const float* __restrict__ degf, const float* __restrict__ Wd,
        const float* __restrict__ bd, const float* __restrict__ Wg,
        const float* __restrict__ bg, const float* __restrict__ bm,
        float* __restrict__ out, int N, float invN) {
    __shared__ short As[64][48];    // 32 used + pad to 48 (96B rows: <=2-way bank alias)
    __shared__ short Bs[128][48];
    __shared__ float sc[128], sh[128];
    const int t = threadIdx.x;
    const int lane = t & 63;
    const int wave = t >> 6;
    const int wr = wave >> 1, wc = wave & 1;
    const int r0 = blockIdx.x * 64;
    const int ASTRIDE = (MODE == 2) ? 128 : K;

    if (MODE >= 1) {
        if (t < 128) {
            float mean = stats[t] * invN;
            float var = stats[128 + t] * invN - mean * mean;
            float scale = g[t] * rsqrtf(var + BN_EPS);
            sc[t] = scale;
            sh[t] = be[t] - mean * scale;
        }
        __syncthreads();
    }

    f32x4 acc[2][4];
#pragma unroll
    for (int m = 0; m < 2; ++m)
#pragma unroll
        for (int n = 0; n < 4; ++n) acc[m][n] = (f32x4){0.f, 0.f, 0.f, 0.f};

    for (int kt = 0; kt < K; kt += 32) {
        // ---- stage A: 64 rows x 32 k (thread: row t>>2, 8 consecutive k) ----
        {
            int r = t >> 2;
            int kk0 = (t & 3) * 8;
            int row = r0 + r;
            int kbase = kt + kk0;
            float v[8];
            if (row < N) {
                if (MODE == 2 && kbase >= 128) {
                    const float* Wv; const float* bv; float s;
                    int cb;
                    if (kbase >= 256) { Wv = Wg; bv = bg; s = degf[row]; cb = kbase - 256; }
                    else              { Wv = Wd; bv = bd; s = dist[row]; cb = kbase - 128; }
#pragma unroll
                    for (int j = 0; j < 8; ++j) v[j] = fmaxf(0.f, s * Wv[cb + j] + bv[cb + j]);
                } else {
                    const float4 f0 = *(const float4*)(A + (size_t)row * ASTRIDE + kbase);
                    const float4 f1 = *(const float4*)(A + (size_t)row * ASTRIDE + kbase + 4);
                    v[0] = f0.x; v[1] = f0.y; v[2] = f0.z; v[3] = f0.w;
                    v[4] = f1.x; v[5] = f1.y; v[6] = f1.z; v[7] = f1.w;
                    if (MODE >= 1) {
#pragma unroll
                        for (int j = 0; j < 8; ++j) v[j] = fmaxf(0.f, v[j] * sc[kbase + j] + sh[kbase + j]);
                    }
                }
            } else {
#pragma unroll
                for (int j = 0; j < 8; ++j) v[j] = 0.f;
            }
            union { short s[8]; int4 q; } pk;
#pragma unroll
            for (int j = 0; j < 8; ++j) pk.s[j] = f2b(v[j]);
            *(int4*)&As[r][kk0] = pk.q;
        }
        // ---- stage B: Bs[c][0..31] = Bt[c][kt..kt+31] (bf16, already transposed) ----
        {
            int c = t >> 1;
            const short* wrow = Bt + (size_t)c * K + kt;
            int half = t & 1;
            *(int4*)&Bs[c][half * 8]      = ((const int4*)wrow)[half];
            *(int4*)&Bs[c][half * 8 + 16] = ((const int4*)wrow)[half + 2];
        }
        __syncthreads();
        // ---- MFMA: wave (wr,wc) computes rows wr*32..+32, cols wc*64..+64 ----
        {
            const int g16 = (lane >> 4) * 8;
            const int rl = lane & 15;
            bf16x8 a0 = *reinterpret_cast<const bf16x8*>(&As[wr * 32 + rl][g16]);
            bf16x8 a1 = *reinterpret_cast<const bf16x8*>(&As[wr * 32 + 16 + rl][g16]);
#pragma unroll
            for (int n = 0; n < 4; ++n) {
                bf16x8 b = *reinterpret_cast<const bf16x8*>(&Bs[wc * 64 + n * 16 + rl][g16]);
                acc[0][n] = __builtin_amdgcn_mfma_f32_16x16x32_bf16(a0, b, acc[0][n], 0, 0, 0);
                acc[1][n] = __builtin_amdgcn_mfma_f32_16x16x32_bf16(a1, b, acc[1][n], 0, 0, 0);
            }
        }
        __syncthreads();
    }

    // ---- epilogue: C/D layout col=lane&15, row=(lane>>4)*4+reg (m89-verified) ----
    const int rbase = r0 + wr * 32 + (lane >> 4) * 4;
    const int cbase = wc * 64 + (lane & 15);
#pragma unroll
    for (int m = 0; m < 2; ++m) {
#pragma unroll
        for (int n = 0; n < 4; ++n) {
            int col = cbase + n * 16;
            float bias = (MODE == 2) ? bm[col] : 0.f;
#pragma unroll
            for (int j = 0; j < 4; ++j) {
                int row = rbase + m * 16 + j;
                if (row < N) out[(size_t)row * 128 + col] = acc[m][n][j] + bias;
            }
        }
    }
}

// ---------------- CSR gather aggregation (no atomics) ----------------
__global__ void k_gather(const float* __restrict__ h, const int* __restrict__ esrc,
                         const float* __restrict__ enorm, const int* __restrict__ rowptr,
                         const int* __restrict__ rowend, const float* __restrict__ dinv,
                         const float* __restrict__ bias, float* __restrict__ agg, int N) {
    int node = blockIdx.x * 4 + (threadIdx.x >> 6);  // one wave per node
    int lane = threadIdx.x & 63;
    if (node >= N) return;
    int start = rowptr[node], end = rowend[node];
    float di = dinv[node];
    float sl = di * di;
    float2 hv = ((const float2*)(h + (size_t)node * 128))[lane];
    float2 bv = ((const float2*)bias)[lane];
    float ax = sl * hv.x + bv.x;
    float ay = sl * hv.y + bv.y;
    for (int j = start; j < end; ++j) {
        int s = esrc[j];
        float w = enorm[j];
        float2 v = ((const float2*)(h + (size_t)s * 128))[lane];
        ax += w * v.x;
        ay += w * v.y;
    }
    float2 o = {ax, ay};
    ((float2*)(agg + (size_t)node * 128))[lane] = o;
}

// ---------------- batchnorm stats ----------------
__global__ void k_bn_stats(const float* __restrict__ h, float* __restrict__ stats, int N) {
    int c = threadIdx.x & 127;
    int rowStart = blockIdx.x * 2 + (threadIdx.x >> 7);
    int rowStride = gridDim.x * 2;
    float s = 0.f, q = 0.f;
    for (int n = rowStart; n < N; n += rowStride) {
        float v = h[(size_t)n * 128 + c];
        s += v;
        q += v * v;
    }
    atomicAdd(&stats[c], s);
    atomicAdd(&stats[128 + c], q);
}

extern "C" void kernel_launch(void* const* d_in, const int* in_sizes, int n_in,
                              void* d_out, int out_size, void* d_ws, size_t ws_size,
                              hipStream_t stream) {
    const float* x    = (const float*)d_in[0];
    const int*   ei   = (const int*)d_in[1];
    const float* ew   = (const float*)d_in[2];
    const float* dist = (const float*)d_in[3];
    const float* degf = (const float*)d_in[4];
    const float* W1   = (const float*)d_in[5];
    const float* b1   = (const float*)d_in[6];
    const float* W2   = (const float*)d_in[7];
    const float* b2   = (const float*)d_in[8];
    const float* g1   = (const float*)d_in[9];
    const float* be1  = (const float*)d_in[10];
    const float* g2   = (const float*)d_in[11];
    const float* be2  = (const float*)d_in[12];
    const float* Wd   = (const float*)d_in[13];
    const float* bd   = (const float*)d_in[14];
    const float* Wg   = (const float*)d_in[15];
    const float* bg   = (const float*)d_in[16];
    const float* Wm   = (const float*)d_in[17];
    const float* bm   = (const float*)d_in[18];

    const int IN = 64;
    const int N = in_sizes[0] / IN;   // 100000
    const int E = in_sizes[1] / 2;    // 1600000

    // ws layout (4B units): cnt[N] | deg[N] | stats[512] | rowptr[N] | cur[N] |
    // src32[E] | dst32[E] | esrc[E] | enorm[E] | blktot[256] | agg[N*128] | wt (bf16)
    int*   cnt    = (int*)d_ws;
    float* deg    = (float*)(cnt + N);
    float* stats  = deg + N;
    int*   rowptr = (int*)(stats + 512);
    int*   cur    = rowptr + N;
    int*   src32  = cur + N;
    int*   dst32  = src32 + E;
    int*   esrc   = dst32 + E;
    float* enorm  = (float*)(esrc + E);
    int*   blktot = (int*)(enorm + E);
    float* agg    = (float*)(blktot + 256);
    short* w1t    = (short*)(agg + (size_t)N * 128);  // [128][64]
    short* w2t    = w1t + 128 * 64;                   // [128][128]
    short* wmt    = w2t + 128 * 128;                  // [128][384]
    float* hbuf   = (float*)d_out;                    // staging; overwritten at end
    float* dinv   = deg;

    hipMemsetAsync(cnt, 0, (size_t)(2 * N + 512) * sizeof(float), stream);

    const int nbE = (E + 255) / 256;
    const int nbN = (N + 255) / 256;
    const int nscan = (N + 1023) / 1024;

    k_prep_wt<<<288, 256, 0, stream>>>(W1, W2, Wm, w1t, w2t, wmt);
    k_canon_hist<<<nbE, 256, 0, stream>>>(ei, ew, src32, dst32, cnt, deg, E);
    k_dinv<<<nbN, 256, 0, stream>>>(deg, N);
    k_scan1<<<nscan, 256, 0, stream>>>(cnt, rowptr, blktot, N);
    k_scan2<<<1, 256, 0, stream>>>(blktot, nscan);
    k_scan3<<<nbN, 256, 0, stream>>>(rowptr, blktot, cur, N);
    k_scatter<<<nbE, 256, 0, stream>>>(src32, dst32, ew, dinv, cur, esrc, enorm, E);

    const int nbGe = (N + 63) / 64;   // GEMM blocks
    const int nbG  = (N + 3) / 4;     // gather blocks
    const float invN = 1.0f / (float)N;

    // layer 1: x @ W1 -> hbuf; CSR gather(+b1) -> agg; stats1
    k_gemm<64, 0><<<nbGe, 256, 0, stream>>>(x, w1t, nullptr, nullptr, nullptr, nullptr,
                                            nullptr, nullptr, nullptr, nullptr, nullptr,
                                            nullptr, hbuf, N, invN);
    k_gather<<<nbG, 256, 0, stream>>>(hbuf, esrc, enorm, rowptr, cur, dinv, b1, agg, N);
    k_bn_stats<<<512, 256, 0, stream>>>(agg, stats, N);

    // layer 2: BN1+ReLU(agg) @ W2 -> hbuf; CSR gather(+b2) -> agg; stats2
    k_gemm<128, 1><<<nbGe, 256, 0, stream>>>(agg, w2t, stats, g1, be1, nullptr,
                                             nullptr, nullptr, nullptr, nullptr, nullptr,
                                             nullptr, hbuf, N, invN);
    k_gather<<<nbG, 256, 0, stream>>>(hbuf, esrc, enorm, rowptr, cur, dinv, b2, agg, N);
    k_bn_stats<<<512, 256, 0, stream>>>(agg, stats + 256, N);

    // final: [BN2+ReLU(agg) | relu(dist*Wd+bd) | relu(degf*Wg+bg)] @ Wm + bm -> d_out
    k_gemm<384, 2><<<nbGe, 256, 0, stream>>>(agg, wmt, stats + 256, g2, be2, dist,
                                             degf, Wd, bd, Wg, bg,
                                             bm, (float*)d_out, N, invN);
}

// Round 6
// 783.050 us; speedup vs baseline: 7.5509x; 1.0116x over previous
//
#include <hip/hip_runtime.h>
#include <hip/hip_bf16.h>

#define BN_EPS 1e-5f

typedef __attribute__((ext_vector_type(8))) short bf16x8;
typedef __attribute__((ext_vector_type(4))) float f32x4;

__device__ __forceinline__ short f2b(float f) {
    __hip_bfloat16 h = __float2bfloat16(f);
    return *reinterpret_cast<short*>(&h);
}
__device__ __forceinline__ float bu2f(unsigned short u) {
    unsigned int x = ((unsigned int)u) << 16;
    return __uint_as_float(x);
}
__device__ __forceinline__ float lo16(unsigned int v) { return __uint_as_float(v << 16); }
__device__ __forceinline__ float hi16(unsigned int v) { return __uint_as_float(v & 0xffff0000u); }

// ---------------- canonicalize edge_index (+ dst histogram + weighted degree) ----------------
__global__ void k_canon_hist(const int* __restrict__ ei, const float* __restrict__ ew,
                             int* __restrict__ src32, int* __restrict__ dst32,
                             int* __restrict__ cnt, float* __restrict__ deg, int E) {
    __shared__ int is64;
    if (threadIdx.x == 0) {
        int any = 0;
        for (int j = 1; j < 512; j += 2) any |= ei[j];
        is64 = (any == 0);
    }
    __syncthreads();
    int e = blockIdx.x * blockDim.x + threadIdx.x;
    if (e < E) {
        int s, d;
        if (is64) { s = ei[2 * e]; d = ei[2 * E + 2 * e]; }
        else      { s = ei[e];     d = ei[E + e]; }
        src32[e] = s;
        dst32[e] = d;
        atomicAdd(&cnt[d], 1);
        atomicAdd(&deg[d], ew[e]);
    }
}

__global__ void k_dinv(float* deg, int N) {
    int i = blockIdx.x * blockDim.x + threadIdx.x;
    if (i < N) deg[i] = rsqrtf(deg[i] + 1.0f);  // +1 = self-loop
}

// ---------------- exclusive scan of cnt[N] -> rowptr[N] ----------------
__global__ void k_scan1(const int* __restrict__ cnt, int* __restrict__ rowptr,
                        int* __restrict__ blktot, int N) {
    __shared__ int lds[256];
    int tid = threadIdx.x;
    int base = blockIdx.x * 1024 + tid * 4;
    int v[4]; int s = 0;
#pragma unroll
    for (int j = 0; j < 4; ++j) { v[j] = (base + j < N) ? cnt[base + j] : 0; s += v[j]; }
    lds[tid] = s;
    __syncthreads();
    for (int off = 1; off < 256; off <<= 1) {
        int t = (tid >= off) ? lds[tid - off] : 0;
        __syncthreads();
        lds[tid] += t;
        __syncthreads();
    }
    if (tid == 255) blktot[blockIdx.x] = lds[255];
    int run = lds[tid] - s;
#pragma unroll
    for (int j = 0; j < 4; ++j) {
        if (base + j < N) rowptr[base + j] = run;
        run += v[j];
    }
}

__global__ void k_scan2(int* blktot, int nb) {
    __shared__ int lds[256];
    int tid = threadIdx.x;
    int v = (tid < nb) ? blktot[tid] : 0;
    lds[tid] = v;
    __syncthreads();
    for (int off = 1; off < 256; off <<= 1) {
        int t = (tid >= off) ? lds[tid - off] : 0;
        __syncthreads();
        lds[tid] += t;
        __syncthreads();
    }
    if (tid < nb) blktot[tid] = lds[tid] - v;
}

__global__ void k_scan3(int* __restrict__ rowptr, const int* __restrict__ blktot,
                        int* __restrict__ cur, int N) {
    int i = blockIdx.x * blockDim.x + threadIdx.x;
    if (i < N) {
        int v = rowptr[i] + blktot[i >> 10];
        rowptr[i] = v;
        cur[i] = v;
    }
}

// scatter edges into packed CSR: ecsr[pos] = {src, bits(norm)}
__global__ void k_scatter(const int* __restrict__ src32, const int* __restrict__ dst32,
                          const float* __restrict__ ew, const float* __restrict__ dinv,
                          int* __restrict__ cur, int2* __restrict__ ecsr, int E) {
    int e = blockIdx.x * blockDim.x + threadIdx.x;
    if (e < E) {
        int s = src32[e], d = dst32[e];
        int pos = atomicAdd(&cur[d], 1);
        int2 rec;
        rec.x = s;
        rec.y = __float_as_int(dinv[s] * ew[e] * dinv[d]);
        ecsr[pos] = rec;
    }
}

// ---------------- weight transpose (bf16) + x -> bf16 table ----------------
__global__ void k_prep_wt(const float* __restrict__ W1, const float* __restrict__ W2,
                          const float* __restrict__ Wm, short* __restrict__ w1t,
                          short* __restrict__ w2t, short* __restrict__ wmt) {
    int idx = blockIdx.x * 256 + threadIdx.x;
    if (idx < 128 * 64) {
        int c = idx >> 6, k = idx & 63;
        w1t[idx] = f2b(W1[k * 128 + c]);
    } else if (idx < 128 * 64 + 128 * 128) {
        int i = idx - 128 * 64; int c = i >> 7, k = i & 127;
        w2t[i] = f2b(W2[k * 128 + c]);
    } else if (idx < 128 * 64 + 128 * 128 + 128 * 384) {
        int i = idx - (128 * 64 + 128 * 128); int c = i / 384, k = i % 384;
        wmt[i] = f2b(Wm[k * 128 + c]);
    }
}

__global__ void k_prep_xb(const float* __restrict__ x, unsigned short* __restrict__ xb,
                          int total4) {
    int i = blockIdx.x * blockDim.x + threadIdx.x;  // total4 = N*64/4
    if (i >= total4) return;
    float4 v = ((const float4*)x)[i];
    ushort4 o;
    o.x = (unsigned short)f2b(v.x);
    o.y = (unsigned short)f2b(v.y);
    o.z = (unsigned short)f2b(v.z);
    o.w = (unsigned short)f2b(v.w);
    ((ushort4*)xb)[i] = o;
}

// ---------------- MFMA GEMM ----------------
// MODE 0: K=64,  A f32 (agg0),  out bf16, epilogue bias eb (b1)
// MODE 1: K=128, A bf16 (h1c) + BN(stats,g,be)+ReLU on load, out bf16, no bias
// MODE 2: K=384 virtual, A f32 (h2c, stride 128) BN2+ReLU | dist | degf features,
//         out f32 + epilogue bias eb (bm)
template <int K, int MODE>
__global__ __launch_bounds__(256) void k_gemm(
        const void* __restrict__ A, const short* __restrict__ Bt,
        const float* __restrict__ stats, const float* __restrict__ g,
        const float* __restrict__ be, const float* __restrict__ dist,
        const float* __restrict__ degf, const float* __restrict__ Wd,
        const float* __restrict__ bd, const float* __restrict__ Wg,
        const float* __restrict__ bg, const float* __restrict__ eb,
        void* __restrict__ out, int N, float invN) {
    __shared__ short As[64][48];    // 32 used + pad to 48
    __shared__ short Bs[128][48];
    __shared__ float sc[128], sh[128];
    const int t = threadIdx.x;
    const int lane = t & 63;
    const int wave = t >> 6;
    const int wr = wave >> 1, wc = wave & 1;
    const int r0 = blockIdx.x * 64;

    if (MODE >= 1) {
        if (t < 128) {
            float mean = stats[t] * invN;
            float var = stats[128 + t] * invN - mean * mean;
            float scale = g[t] * rsqrtf(var + BN_EPS);
            sc[t] = scale;
            sh[t] = be[t] - mean * scale;
        }
        __syncthreads();
    }

    f32x4 acc[2][4];
#pragma unroll
    for (int m = 0; m < 2; ++m)
#pragma unroll
        for (int n = 0; n < 4; ++n) acc[m][n] = (f32x4){0.f, 0.f, 0.f, 0.f};

    for (int kt = 0; kt < K; kt += 32) {
        // ---- stage A ----
        {
            int r = t >> 2;
            int kk0 = (t & 3) * 8;
            int row = r0 + r;
            int kbase = kt + kk0;
            float v[8];
            if (row < N) {
                if (MODE == 2 && kbase >= 128) {
                    const float* Wv; const float* bv; float s;
                    int cb;
                    if (kbase >= 256) { Wv = Wg; bv = bg; s = degf[row]; cb = kbase - 256; }
                    else              { Wv = Wd; bv = bd; s = dist[row]; cb = kbase - 128; }
#pragma unroll
                    for (int j = 0; j < 8; ++j) v[j] = fmaxf(0.f, s * Wv[cb + j] + bv[cb + j]);
                } else if (MODE == 1) {
                    const unsigned short* Ab = (const unsigned short*)A;
                    union { int4 q; unsigned short s[8]; } u;
                    u.q = *(const int4*)(Ab + (size_t)row * 128 + kbase);
#pragma unroll
                    for (int j = 0; j < 8; ++j)
                        v[j] = fmaxf(0.f, bu2f(u.s[j]) * sc[kbase + j] + sh[kbase + j]);
                } else {
                    const int ASTRIDE = (MODE == 2) ? 128 : K;
                    const float* Af = (const float*)A;
                    const float4 f0 = *(const float4*)(Af + (size_t)row * ASTRIDE + kbase);
                    const float4 f1 = *(const float4*)(Af + (size_t)row * ASTRIDE + kbase + 4);
                    v[0] = f0.x; v[1] = f0.y; v[2] = f0.z; v[3] = f0.w;
                    v[4] = f1.x; v[5] = f1.y; v[6] = f1.z; v[7] = f1.w;
                    if (MODE == 2) {
#pragma unroll
                        for (int j = 0; j < 8; ++j)
                            v[j] = fmaxf(0.f, v[j] * sc[kbase + j] + sh[kbase + j]);
                    }
                }
            } else {
#pragma unroll
                for (int j = 0; j < 8; ++j) v[j] = 0.f;
            }
            union { short s[8]; int4 q; } pk;
#pragma unroll
            for (int j = 0; j < 8; ++j) pk.s[j] = f2b(v[j]);
            *(int4*)&As[r][kk0] = pk.q;
        }
        // ---- stage B ----
        {
            int c = t >> 1;
            const short* wrow = Bt + (size_t)c * K + kt;
            int half = t & 1;
            *(int4*)&Bs[c][half * 8]      = ((const int4*)wrow)[half];
            *(int4*)&Bs[c][half * 8 + 16] = ((const int4*)wrow)[half + 2];
        }
        __syncthreads();
        // ---- MFMA ----
        {
            const int g16 = (lane >> 4) * 8;
            const int rl = lane & 15;
            bf16x8 a0 = *reinterpret_cast<const bf16x8*>(&As[wr * 32 + rl][g16]);
            bf16x8 a1 = *reinterpret_cast<const bf16x8*>(&As[wr * 32 + 16 + rl][g16]);
#pragma unroll
            for (int n = 0; n < 4; ++n) {
                bf16x8 b = *reinterpret_cast<const bf16x8*>(&Bs[wc * 64 + n * 16 + rl][g16]);
                acc[0][n] = __builtin_amdgcn_mfma_f32_16x16x32_bf16(a0, b, acc[0][n], 0, 0, 0);
                acc[1][n] = __builtin_amdgcn_mfma_f32_16x16x32_bf16(a1, b, acc[1][n], 0, 0, 0);
            }
        }
        __syncthreads();
    }

    // ---- epilogue (C/D: col=lane&15, row=(lane>>4)*4+reg; m89-verified) ----
    const int rbase = r0 + wr * 32 + (lane >> 4) * 4;
    const int cbase = wc * 64 + (lane & 15);
#pragma unroll
    for (int m = 0; m < 2; ++m) {
#pragma unroll
        for (int n = 0; n < 4; ++n) {
            int col = cbase + n * 16;
            float bias = (MODE != 1) ? eb[col] : 0.f;
#pragma unroll
            for (int j = 0; j < 4; ++j) {
                int row = rbase + m * 16 + j;
                if (row < N) {
                    float val = acc[m][n][j] + bias;
                    if (MODE == 2) ((float*)out)[(size_t)row * 128 + col] = val;
                    else ((unsigned short*)out)[(size_t)row * 128 + col] = (unsigned short)f2b(val);
                }
            }
        }
    }
}

// ---------------- CSR gathers ----------------
// agg0[n][c] = dinv[n]^2 * xb[n][c] + sum enorm * xb[src][c]   (64-wide, bf16 table)
__global__ void k_gather64(const unsigned short* __restrict__ xb, const int2* __restrict__ ecsr,
                           const int* __restrict__ rowptr, const int* __restrict__ rowend,
                           const float* __restrict__ dinv, float* __restrict__ agg0, int N) {
    int node = blockIdx.x * 4 + (threadIdx.x >> 6);
    if (node >= N) return;
    int lane = threadIdx.x & 63;
    int start = rowptr[node], end = rowend[node];
    float di = dinv[node];
    float ax = di * di * bu2f(xb[(size_t)node * 64 + lane]);
    for (int j = start; j < end; ++j) {
        int2 e = ecsr[j];
        ax += __int_as_float(e.y) * bu2f(xb[(size_t)e.x * 64 + lane]);
    }
    agg0[(size_t)node * 64 + lane] = ax;
}

// h2c[n][c] = dinv[n]^2 * t2[n][c] + b[c] + sum enorm * t2[src][c]  (128-wide bf16 table)
__global__ void k_gather128b(const unsigned int* __restrict__ t2, const int2* __restrict__ ecsr,
                             const int* __restrict__ rowptr, const int* __restrict__ rowend,
                             const float* __restrict__ dinv, const float* __restrict__ bias,
                             float* __restrict__ out, int N) {
    int node = blockIdx.x * 4 + (threadIdx.x >> 6);
    if (node >= N) return;
    int lane = threadIdx.x & 63;
    int start = rowptr[node], end = rowend[node];
    float di = dinv[node];
    float sl = di * di;
    unsigned int hv = t2[(size_t)node * 64 + lane];
    float2 bv = ((const float2*)bias)[lane];
    float ax = sl * lo16(hv) + bv.x;
    float ay = sl * hi16(hv) + bv.y;
    for (int j = start; j < end; ++j) {
        int2 e = ecsr[j];
        float w = __int_as_float(e.y);
        unsigned int v = t2[(size_t)e.x * 64 + lane];
        ax += w * lo16(v);
        ay += w * hi16(v);
    }
    float2 o = {ax, ay};
    ((float2*)(out + (size_t)node * 128))[lane] = o;
}

// ---------------- batchnorm stats ----------------
__global__ void k_bn_stats_b(const unsigned int* __restrict__ h, float* __restrict__ stats, int N) {
    int pair = threadIdx.x & 63;  // channels 2*pair, 2*pair+1
    int rowStart = blockIdx.x * 4 + (threadIdx.x >> 6);
    int rowStride = gridDim.x * 4;
    float s0 = 0.f, q0 = 0.f, s1 = 0.f, q1 = 0.f;
    for (int n = rowStart; n < N; n += rowStride) {
        unsigned int v = h[(size_t)n * 64 + pair];
        float a = lo16(v), b = hi16(v);
        s0 += a; q0 += a * a;
        s1 += b; q1 += b * b;
    }
    atomicAdd(&stats[2 * pair], s0);
    atomicAdd(&stats[128 + 2 * pair], q0);
    atomicAdd(&stats[2 * pair + 1], s1);
    atomicAdd(&stats[128 + 2 * pair + 1], q1);
}

__global__ void k_bn_stats(const float* __restrict__ h, float* __restrict__ stats, int N) {
    int c = threadIdx.x & 127;
    int rowStart = blockIdx.x * 2 + (threadIdx.x >> 7);
    int rowStride = gridDim.x * 2;
    float s = 0.f, q = 0.f;
    for (int n = rowStart; n < N; n += rowStride) {
        float v = h[(size_t)n * 128 + c];
        s += v;
        q += v * v;
    }
    atomicAdd(&stats[c], s);
    atomicAdd(&stats[128 + c], q);
}

extern "C" void kernel_launch(void* const* d_in, const int* in_sizes, int n_in,
                              void* d_out, int out_size, void* d_ws, size_t ws_size,
                              hipStream_t stream) {
    const float* x    = (const float*)d_in[0];
    const int*   ei   = (const int*)d_in[1];
    const float* ew   = (const float*)d_in[2];
    const float* dist = (const float*)d_in[3];
    const float* degf = (const float*)d_in[4];
    const float* W1   = (const float*)d_in[5];
    const float* b1   = (const float*)d_in[6];
    const float* W2   = (const float*)d_in[7];
    const float* b2   = (const float*)d_in[8];
    const float* g1   = (const float*)d_in[9];
    const float* be1  = (const float*)d_in[10];
    const float* g2   = (const float*)d_in[11];
    const float* be2  = (const float*)d_in[12];
    const float* Wd   = (const float*)d_in[13];
    const float* bd   = (const float*)d_in[14];
    const float* Wg   = (const float*)d_in[15];
    const float* bg   = (const float*)d_in[16];
    const float* Wm   = (const float*)d_in[17];
    const float* bm   = (const float*)d_in[18];

    const int IN = 64;
    const int N = in_sizes[0] / IN;   // 100000
    const int E = in_sizes[1] / 2;    // 1600000

    // ws (4B words): cnt[N] deg[N] stats[512] rowptr[N] cur[N] src32[E] dst32[E]
    //   ecsr[2E] blktot[256] h2c[N*128] wt(bf16) xb(bf16 N*64)   ~= 91.5 MB
    int*   cnt    = (int*)d_ws;
    float* deg    = (float*)(cnt + N);
    float* stats  = deg + N;
    int*   rowptr = (int*)(stats + 512);
    int*   cur    = rowptr + N;
    int*   src32  = cur + N;
    int*   dst32  = src32 + E;
    int2*  ecsr   = (int2*)(dst32 + E);
    int*   blktot = (int*)(ecsr + E);
    float* h2c    = (float*)(blktot + 256);            // N*128 f32
    short* w1t    = (short*)(h2c + (size_t)N * 128);   // [128][64]
    short* w2t    = w1t + 128 * 64;                    // [128][128]
    short* wmt    = w2t + 128 * 128;                   // [128][384]
    unsigned short* xb = (unsigned short*)(wmt + 128 * 384);  // N*64 bf16
    float* dinv   = deg;

    // d_out time-share: h1c bf16 [0, N*128) ushorts; agg0 f32 / t2 bf16 in upper half
    unsigned short* h1c = (unsigned short*)d_out;
    float*          agg0 = (float*)d_out + (size_t)N * 64;
    unsigned short* t2   = (unsigned short*)d_out + (size_t)N * 128;

    hipMemsetAsync(cnt, 0, (size_t)(2 * N + 512) * sizeof(float), stream);

    const int nbE = (E + 255) / 256;
    const int nbN = (N + 255) / 256;
    const int nscan = (N + 1023) / 1024;

    k_prep_wt<<<288, 256, 0, stream>>>(W1, W2, Wm, w1t, w2t, wmt);
    k_prep_xb<<<(N * 16 + 255) / 256, 256, 0, stream>>>(x, xb, N * 16);
    k_canon_hist<<<nbE, 256, 0, stream>>>(ei, ew, src32, dst32, cnt, deg, E);
    k_dinv<<<nbN, 256, 0, stream>>>(deg, N);
    k_scan1<<<nscan, 256, 0, stream>>>(cnt, rowptr, blktot, N);
    k_scan2<<<1, 256, 0, stream>>>(blktot, nscan);
    k_scan3<<<nbN, 256, 0, stream>>>(rowptr, blktot, cur, N);
    k_scatter<<<nbE, 256, 0, stream>>>(src32, dst32, ew, dinv, cur, ecsr, E);

    const int nbGe = (N + 63) / 64;
    const int nbG  = (N + 3) / 4;
    const float invN = 1.0f / (float)N;

    // layer 1: agg0 = A_hat @ x (bf16 table); h1c = agg0 @ W1 + b1 (bf16 out); stats1
    k_gather64<<<nbG, 256, 0, stream>>>(xb, ecsr, rowptr, cur, dinv, agg0, N);
    k_gemm<64, 0><<<nbGe, 256, 0, stream>>>(agg0, w1t, nullptr, nullptr, nullptr, nullptr,
                                            nullptr, nullptr, nullptr, nullptr, nullptr,
                                            b1, h1c, N, invN);
    k_bn_stats_b<<<512, 256, 0, stream>>>((const unsigned int*)h1c, stats, N);

    // layer 2: t2 = BN1ReLU(h1c) @ W2 (bf16 out); h2c = A_hat @ t2 + b2 (f32); stats2
    k_gemm<128, 1><<<nbGe, 256, 0, stream>>>(h1c, w2t, stats, g1, be1, nullptr,
                                             nullptr, nullptr, nullptr, nullptr, nullptr,
                                             nullptr, t2, N, invN);
    k_gather128b<<<nbG, 256, 0, stream>>>((const unsigned int*)t2, ecsr, rowptr, cur,
                                          dinv, b2, h2c, N);
    k_bn_stats<<<512, 256, 0, stream>>>(h2c, stats + 256, N);

    // final: [BN2ReLU(h2c) | relu(dist*Wd+bd) | relu(degf*Wg+bg)] @ Wm + bm -> d_out f32
    k_gemm<384, 2><<<nbGe, 256, 0, stream>>>(h2c, wmt, stats + 256, g2, be2, dist,
                                             degf, Wd, bd, Wg, bg,
                                             bm, d_out, N, invN);
}

// Round 7
// 527.534 us; speedup vs baseline: 11.2082x; 1.4844x over previous
//
#include <hip/hip_runtime.h>
#include <hip/hip_bf16.h>

#define BN_EPS 1e-5f

typedef __attribute__((ext_vector_type(8))) short bf16x8;
typedef __attribute__((ext_vector_type(4))) float f32x4;

__device__ __forceinline__ short f2b(float f) {
    __hip_bfloat16 h = __float2bfloat16(f);
    return *reinterpret_cast<short*>(&h);
}
__device__ __forceinline__ float bu2f(unsigned short u) {
    return __uint_as_float(((unsigned int)u) << 16);
}
__device__ __forceinline__ float lo16(unsigned int v) { return __uint_as_float(v << 16); }
__device__ __forceinline__ float hi16(unsigned int v) { return __uint_as_float(v & 0xffff0000u); }

#define DEG_SCALE 1048576.0f          /* 2^20 */
#define DEG_INV   (1.0f / 1048576.0f)
#define DEG_MASK  ((1ULL << 43) - 1)

// ---------------- int64-vs-int32 storage probe (one block) ----------------
__global__ void k_flag(const int* __restrict__ ei, int* __restrict__ flag) {
    __shared__ int any;
    if (threadIdx.x == 0) any = 0;
    __syncthreads();
    if (ei[2 * threadIdx.x + 1] != 0) atomicOr(&any, 1);
    __syncthreads();
    if (threadIdx.x == 0) *flag = (any == 0);  // all-high-words-zero => int64
}

// ---------------- histogram: packed {cnt|deg} per dst ----------------
__global__ void k_hist(const int* __restrict__ ei, const float* __restrict__ ew,
                       const int* __restrict__ flag, unsigned long long* __restrict__ packed,
                       int E) {
    int e = blockIdx.x * blockDim.x + threadIdx.x;
    if (e >= E) return;
    int d = (*flag) ? ei[2 * E + 2 * e] : ei[E + e];
    unsigned int wf = __float2uint_rn(ew[e] * DEG_SCALE);
    atomicAdd(&packed[d], (1ULL << 43) | (unsigned long long)wf);
}

// ---------------- scan stage 1 fused with unpack (packed -> dinv, rowptr partial) ----------------
__global__ void k_scan1(const unsigned long long* __restrict__ packed,
                        float* __restrict__ dinv, int* __restrict__ rowptr,
                        int* __restrict__ blktot, int N) {
    __shared__ int lds[256];
    int tid = threadIdx.x;
    int base = blockIdx.x * 1024 + tid * 4;
    int v[4]; int s = 0;
#pragma unroll
    for (int j = 0; j < 4; ++j) {
        int idx = base + j;
        if (idx < N) {
            unsigned long long p = packed[idx];
            v[j] = (int)(p >> 43);
            float deg = (float)(p & DEG_MASK) * DEG_INV;
            dinv[idx] = rsqrtf(deg + 1.0f);
        } else v[j] = 0;
        s += v[j];
    }
    lds[tid] = s;
    __syncthreads();
    for (int off = 1; off < 256; off <<= 1) {
        int t = (tid >= off) ? lds[tid - off] : 0;
        __syncthreads();
        lds[tid] += t;
        __syncthreads();
    }
    if (tid == 255) blktot[blockIdx.x] = lds[255];
    int run = lds[tid] - s;
#pragma unroll
    for (int j = 0; j < 4; ++j) {
        if (base + j < N) rowptr[base + j] = run;
        run += v[j];
    }
}

__global__ void k_scan2(int* blktot, int nb) {
    __shared__ int lds[256];
    int tid = threadIdx.x;
    int v = (tid < nb) ? blktot[tid] : 0;
    lds[tid] = v;
    __syncthreads();
    for (int off = 1; off < 256; off <<= 1) {
        int t = (tid >= off) ? lds[tid - off] : 0;
        __syncthreads();
        lds[tid] += t;
        __syncthreads();
    }
    if (tid < nb) blktot[tid] = lds[tid] - v;
}

__global__ void k_scan3(int* __restrict__ rowptr, const int* __restrict__ blktot,
                        int* __restrict__ cur, int N) {
    int i = blockIdx.x * blockDim.x + threadIdx.x;
    if (i < N) {
        int v = rowptr[i] + blktot[i >> 10];
        rowptr[i] = v;
        cur[i] = v;
    }
}

// ---------------- scatter edges into packed CSR (reads ei directly) ----------------
__global__ void k_scatter(const int* __restrict__ ei, const float* __restrict__ ew,
                          const int* __restrict__ flag, const float* __restrict__ dinv,
                          int* __restrict__ cur, int2* __restrict__ ecsr, int E) {
    int e = blockIdx.x * blockDim.x + threadIdx.x;
    if (e >= E) return;
    int s, d;
    if (*flag) { s = ei[2 * e]; d = ei[2 * E + 2 * e]; }
    else       { s = ei[e];     d = ei[E + e]; }
    int pos = atomicAdd(&cur[d], 1);
    int2 rec;
    rec.x = s;
    rec.y = __float_as_int(dinv[s] * ew[e] * dinv[d]);
    ecsr[pos] = rec;
}

// ---------------- weight transpose (bf16) + x -> bf16 table ----------------
__global__ void k_prep_wt(const float* __restrict__ W1, const float* __restrict__ W2,
                          const float* __restrict__ Wm, short* __restrict__ w1t,
                          short* __restrict__ w2t, short* __restrict__ wmt) {
    int idx = blockIdx.x * 256 + threadIdx.x;
    if (idx < 128 * 64) {
        int c = idx >> 6, k = idx & 63;
        w1t[idx] = f2b(W1[k * 128 + c]);
    } else if (idx < 128 * 64 + 128 * 128) {
        int i = idx - 128 * 64; int c = i >> 7, k = i & 127;
        w2t[i] = f2b(W2[k * 128 + c]);
    } else if (idx < 128 * 64 + 128 * 128 + 128 * 384) {
        int i = idx - (128 * 64 + 128 * 128); int c = i / 384, k = i % 384;
        wmt[i] = f2b(Wm[k * 128 + c]);
    }
}

__global__ void k_prep_xb(const float* __restrict__ x, unsigned short* __restrict__ xb,
                          int total4) {
    int i = blockIdx.x * blockDim.x + threadIdx.x;  // total4 = N*16
    if (i >= total4) return;
    float4 v = ((const float4*)x)[i];
    ushort4 o;
    o.x = (unsigned short)f2b(v.x);
    o.y = (unsigned short)f2b(v.y);
    o.z = (unsigned short)f2b(v.z);
    o.w = (unsigned short)f2b(v.w);
    ((ushort4*)xb)[i] = o;
}

// ---------------- MFMA GEMM (A always bf16) ----------------
// MODE 0: K=64  A=agg0[N][64];   out bf16 + bias eb (b1); fused BN-stats -> stats (output)
// MODE 1: K=128 A=h1c[N][128] + BN(stats,g,be)+ReLU on load; out bf16, no bias
// MODE 2: K=384 virtual: k<128 BN2+ReLU(h2c bf16); 128..255 relu(dist*Wd+bd);
//         256..383 relu(degf*Wg+bg); out f32 + bias eb (bm)
template <int K, int MODE>
__global__ __launch_bounds__(256) void k_gemm(
        const unsigned short* __restrict__ A, const short* __restrict__ Bt,
        float* __restrict__ stats, const float* __restrict__ g,
        const float* __restrict__ be, const float* __restrict__ dist,
        const float* __restrict__ degf, const float* __restrict__ Wd,
        const float* __restrict__ bd, const float* __restrict__ Wg,
        const float* __restrict__ bg, const float* __restrict__ eb,
        void* __restrict__ out, int N, float invN) {
    __shared__ short As[64][48];
    __shared__ short Bs[128][48];
    __shared__ float sc[128], sh[128];
    __shared__ float st0[128], st1[128];
    const int t = threadIdx.x;
    const int lane = t & 63;
    const int wave = t >> 6;
    const int wr = wave >> 1, wc = wave & 1;
    const int r0 = blockIdx.x * 64;

    if (MODE >= 1) {
        if (t < 128) {
            float mean = stats[t] * invN;
            float var = stats[128 + t] * invN - mean * mean;
            float scale = g[t] * rsqrtf(var + BN_EPS);
            sc[t] = scale;
            sh[t] = be[t] - mean * scale;
        }
        __syncthreads();
    }
    if (MODE == 0) {
        if (t < 128) { st0[t] = 0.f; st1[t] = 0.f; }
        __syncthreads();
    }

    f32x4 acc[2][4];
#pragma unroll
    for (int m = 0; m < 2; ++m)
#pragma unroll
        for (int n = 0; n < 4; ++n) acc[m][n] = (f32x4){0.f, 0.f, 0.f, 0.f};

    for (int kt = 0; kt < K; kt += 32) {
        // ---- stage A ----
        {
            int r = t >> 2;
            int kk0 = (t & 3) * 8;
            int row = r0 + r;
            int kbase = kt + kk0;
            const int AST = (MODE == 0) ? 64 : 128;
            union { int4 q; unsigned short s[8]; } u;
            if (row < N) {
                if (MODE == 2 && kbase >= 128) {
                    const float* Wv; const float* bv; float sx; int cb;
                    if (kbase >= 256) { Wv = Wg; bv = bg; sx = degf[row]; cb = kbase - 256; }
                    else              { Wv = Wd; bv = bd; sx = dist[row]; cb = kbase - 128; }
#pragma unroll
                    for (int j = 0; j < 8; ++j)
                        u.s[j] = (unsigned short)f2b(fmaxf(0.f, sx * Wv[cb + j] + bv[cb + j]));
                } else if (MODE == 0) {
                    u.q = *(const int4*)(A + (size_t)row * AST + kbase);
                } else {  // MODE 1, or MODE 2 kbase<128: bf16 + BN + ReLU
                    union { int4 q; unsigned short s[8]; } raw;
                    raw.q = *(const int4*)(A + (size_t)row * AST + kbase);
#pragma unroll
                    for (int j = 0; j < 8; ++j)
                        u.s[j] = (unsigned short)f2b(
                            fmaxf(0.f, bu2f(raw.s[j]) * sc[kbase + j] + sh[kbase + j]));
                }
            } else {
                u.q = (int4){0, 0, 0, 0};
            }
            *(int4*)&As[r][kk0] = u.q;
        }
        // ---- stage B ----
        {
            int c = t >> 1;
            const short* wrow = Bt + (size_t)c * K + kt;
            int half = t & 1;
            *(int4*)&Bs[c][half * 8]      = ((const int4*)wrow)[half];
            *(int4*)&Bs[c][half * 8 + 16] = ((const int4*)wrow)[half + 2];
        }
        __syncthreads();
        // ---- MFMA ----
        {
            const int g16 = (lane >> 4) * 8;
            const int rl = lane & 15;
            bf16x8 a0 = *reinterpret_cast<const bf16x8*>(&As[wr * 32 + rl][g16]);
            bf16x8 a1 = *reinterpret_cast<const bf16x8*>(&As[wr * 32 + 16 + rl][g16]);
#pragma unroll
            for (int n = 0; n < 4; ++n) {
                bf16x8 b = *reinterpret_cast<const bf16x8*>(&Bs[wc * 64 + n * 16 + rl][g16]);
                acc[0][n] = __builtin_amdgcn_mfma_f32_16x16x32_bf16(a0, b, acc[0][n], 0, 0, 0);
                acc[1][n] = __builtin_amdgcn_mfma_f32_16x16x32_bf16(a1, b, acc[1][n], 0, 0, 0);
            }
        }
        __syncthreads();
    }

    // ---- epilogue (C/D: col=lane&15, row=(lane>>4)*4+reg; m89-verified) ----
    const int rbase = r0 + wr * 32 + (lane >> 4) * 4;
    const int cbase = wc * 64 + (lane & 15);
#pragma unroll
    for (int n = 0; n < 4; ++n) {
        int col = cbase + n * 16;
        float bias = (MODE != 1) ? eb[col] : 0.f;
        float sl = 0.f, ql = 0.f;
#pragma unroll
        for (int m = 0; m < 2; ++m) {
#pragma unroll
            for (int j = 0; j < 4; ++j) {
                int row = rbase + m * 16 + j;
                if (row < N) {
                    float val = acc[m][n][j] + bias;
                    if (MODE == 2) ((float*)out)[(size_t)row * 128 + col] = val;
                    else ((unsigned short*)out)[(size_t)row * 128 + col] = (unsigned short)f2b(val);
                    if (MODE == 0) { sl += val; ql += val * val; }
                }
            }
        }
        if (MODE == 0) {
            atomicAdd(&st0[col], sl);
            atomicAdd(&st1[col], ql);
        }
    }
    if (MODE == 0) {
        __syncthreads();
        if (t < 128) {
            atomicAdd(&stats[t], st0[t]);
            atomicAdd(&stats[128 + t], st1[t]);
        }
    }
}

// ---------------- CSR gathers (unroll x4) ----------------
// agg0[n][c] = dinv[n]^2 * xb[n][c] + sum enorm * xb[src][c]   (64-wide bf16 -> bf16)
__global__ void k_gather64(const unsigned short* __restrict__ xb, const int2* __restrict__ ecsr,
                           const int* __restrict__ rowptr, const int* __restrict__ rowend,
                           const float* __restrict__ dinv, unsigned short* __restrict__ agg0,
                           int N) {
    int node = blockIdx.x * 4 + (threadIdx.x >> 6);
    if (node >= N) return;
    int lane = threadIdx.x & 63;
    int start = rowptr[node], end = rowend[node];
    float di = dinv[node];
    float ax = di * di * bu2f(xb[(size_t)node * 64 + lane]);
    int j = start;
    for (; j + 4 <= end; j += 4) {
        int2 e0 = ecsr[j], e1 = ecsr[j + 1], e2 = ecsr[j + 2], e3 = ecsr[j + 3];
        float v0 = bu2f(xb[(size_t)e0.x * 64 + lane]);
        float v1 = bu2f(xb[(size_t)e1.x * 64 + lane]);
        float v2 = bu2f(xb[(size_t)e2.x * 64 + lane]);
        float v3 = bu2f(xb[(size_t)e3.x * 64 + lane]);
        ax += __int_as_float(e0.y) * v0 + __int_as_float(e1.y) * v1 +
              __int_as_float(e2.y) * v2 + __int_as_float(e3.y) * v3;
    }
    for (; j < end; ++j) {
        int2 e = ecsr[j];
        ax += __int_as_float(e.y) * bu2f(xb[(size_t)e.x * 64 + lane]);
    }
    agg0[(size_t)node * 64 + lane] = (unsigned short)f2b(ax);
}

// h2c[n][2l..2l+1] = dinv^2 * t2 + b + sum enorm * t2[src]   (128-wide bf16 -> bf16)
__global__ void k_gather128b(const unsigned int* __restrict__ t2, const int2* __restrict__ ecsr,
                             const int* __restrict__ rowptr, const int* __restrict__ rowend,
                             const float* __restrict__ dinv, const float* __restrict__ bias,
                             unsigned int* __restrict__ h2c, int N) {
    int node = blockIdx.x * 4 + (threadIdx.x >> 6);
    if (node >= N) return;
    int lane = threadIdx.x & 63;
    int start = rowptr[node], end = rowend[node];
    float di = dinv[node];
    float sl = di * di;
    unsigned int hv = t2[(size_t)node * 64 + lane];
    float2 bv = ((const float2*)bias)[lane];
    float ax = sl * lo16(hv) + bv.x;
    float ay = sl * hi16(hv) + bv.y;
    int j = start;
    for (; j + 4 <= end; j += 4) {
        int2 e0 = ecsr[j], e1 = ecsr[j + 1], e2 = ecsr[j + 2], e3 = ecsr[j + 3];
        unsigned int v0 = t2[(size_t)e0.x * 64 + lane];
        unsigned int v1 = t2[(size_t)e1.x * 64 + lane];
        unsigned int v2 = t2[(size_t)e2.x * 64 + lane];
        unsigned int v3 = t2[(size_t)e3.x * 64 + lane];
        float w0 = __int_as_float(e0.y), w1 = __int_as_float(e1.y);
        float w2 = __int_as_float(e2.y), w3 = __int_as_float(e3.y);
        ax += w0 * lo16(v0) + w1 * lo16(v1) + w2 * lo16(v2) + w3 * lo16(v3);
        ay += w0 * hi16(v0) + w1 * hi16(v1) + w2 * hi16(v2) + w3 * hi16(v3);
    }
    for (; j < end; ++j) {
        int2 e = ecsr[j];
        float w = __int_as_float(e.y);
        unsigned int v = t2[(size_t)e.x * 64 + lane];
        ax += w * lo16(v);
        ay += w * hi16(v);
    }
    unsigned int packed = (unsigned int)(unsigned short)f2b(ax) |
                          ((unsigned int)(unsigned short)f2b(ay) << 16);
    h2c[(size_t)node * 64 + lane] = packed;
}

// ---------------- batchnorm stats over bf16-pair table ----------------
__global__ void k_bn_stats_b(const unsigned int* __restrict__ h, float* __restrict__ stats,
                             int N) {
    int pair = threadIdx.x & 63;
    int rowStart = blockIdx.x * 4 + (threadIdx.x >> 6);
    int rowStride = gridDim.x * 4;
    float s0 = 0.f, q0 = 0.f, s1 = 0.f, q1 = 0.f;
    for (int n = rowStart; n < N; n += rowStride) {
        unsigned int v = h[(size_t)n * 64 + pair];
        float a = lo16(v), b = hi16(v);
        s0 += a; q0 += a * a;
        s1 += b; q1 += b * b;
    }
    atomicAdd(&stats[2 * pair], s0);
    atomicAdd(&stats[128 + 2 * pair], q0);
    atomicAdd(&stats[2 * pair + 1], s1);
    atomicAdd(&stats[128 + 2 * pair + 1], q1);
}

extern "C" void kernel_launch(void* const* d_in, const int* in_sizes, int n_in,
                              void* d_out, int out_size, void* d_ws, size_t ws_size,
                              hipStream_t stream) {
    const float* x    = (const float*)d_in[0];
    const int*   ei   = (const int*)d_in[1];
    const float* ew   = (const float*)d_in[2];
    const float* dist = (const float*)d_in[3];
    const float* degf = (const float*)d_in[4];
    const float* W1   = (const float*)d_in[5];
    const float* b1   = (const float*)d_in[6];
    const float* W2   = (const float*)d_in[7];
    const float* b2   = (const float*)d_in[8];
    const float* g1   = (const float*)d_in[9];
    const float* be1  = (const float*)d_in[10];
    const float* g2   = (const float*)d_in[11];
    const float* be2  = (const float*)d_in[12];
    const float* Wd   = (const float*)d_in[13];
    const float* bd   = (const float*)d_in[14];
    const float* Wg   = (const float*)d_in[15];
    const float* bg   = (const float*)d_in[16];
    const float* Wm   = (const float*)d_in[17];
    const float* bm   = (const float*)d_in[18];

    const int IN = 64;
    const int N = in_sizes[0] / IN;   // 100000
    const int E = in_sizes[1] / 2;    // 1600000

    // ws layout (4B words):
    // packed[2N] | stats[512] | flag+pad[128] | rowptr[N] | cur[N] | dinv[N] |
    // blktot[256] | ecsr[2E] | h2c[64N] | agg0[32N] | xb[32N] | w1t/w2t/wmt[36864]
    unsigned long long* packed = (unsigned long long*)d_ws;
    float* stats  = (float*)d_ws + 2 * (size_t)N;
    int*   flag   = (int*)(stats + 512);
    int*   rowptr = flag + 128;
    int*   cur    = rowptr + N;
    float* dinv   = (float*)(cur + N);
    int*   blktot = (int*)(dinv + N);
    int2*  ecsr   = (int2*)(blktot + 256);
    unsigned int*   h2c  = (unsigned int*)(ecsr + E);          // N*128 bf16
    unsigned short* agg0 = (unsigned short*)(h2c + (size_t)N * 64);  // N*64 bf16
    unsigned short* xb   = agg0 + (size_t)N * 64;              // N*64 bf16
    short* w1t    = (short*)(xb + (size_t)N * 64);             // [128][64]
    short* w2t    = w1t + 128 * 64;                            // [128][128]
    short* wmt    = w2t + 128 * 128;                           // [128][384]

    // d_out time-share (bf16 staging, overwritten by final f32 GEMM)
    unsigned short* h1c = (unsigned short*)d_out;              // N*128 bf16
    unsigned int*   t2  = (unsigned int*)d_out + (size_t)N * 64;  // N*128 bf16 (pairs)

    hipMemsetAsync(packed, 0, (2 * (size_t)N + 512) * sizeof(float) * 1, stream);
    // note: packed is 2N words (8B*N) + stats 512 words, contiguous

    const int nbE = (E + 255) / 256;
    const int nbN = (N + 255) / 256;
    const int nscan = (N + 1023) / 1024;

    k_flag<<<1, 256, 0, stream>>>(ei, flag);
    k_prep_wt<<<288, 256, 0, stream>>>(W1, W2, Wm, w1t, w2t, wmt);
    k_prep_xb<<<(N * 16 + 255) / 256, 256, 0, stream>>>(x, xb, N * 16);
    k_hist<<<nbE, 256, 0, stream>>>(ei, ew, flag, packed, E);
    k_scan1<<<nscan, 256, 0, stream>>>(packed, dinv, rowptr, blktot, N);
    k_scan2<<<1, 256, 0, stream>>>(blktot, nscan);
    k_scan3<<<nbN, 256, 0, stream>>>(rowptr, blktot, cur, N);
    k_scatter<<<nbE, 256, 0, stream>>>(ei, ew, flag, dinv, cur, ecsr, E);

    const int nbGe = (N + 63) / 64;
    const int nbG  = (N + 3) / 4;
    const float invN = 1.0f / (float)N;

    // layer 1: agg0 = A_hat @ x; h1c = agg0 @ W1 + b1 (stats1 fused in epilogue)
    k_gather64<<<nbG, 256, 0, stream>>>(xb, ecsr, rowptr, cur, dinv, agg0, N);
    k_gemm<64, 0><<<nbGe, 256, 0, stream>>>(agg0, w1t, stats, nullptr, nullptr, nullptr,
                                            nullptr, nullptr, nullptr, nullptr, nullptr,
                                            b1, h1c, N, invN);

    // layer 2: t2 = BN1ReLU(h1c) @ W2; h2c = A_hat @ t2 + b2; stats2
    k_gemm<128, 1><<<nbGe, 256, 0, stream>>>(h1c, w2t, stats, g1, be1, nullptr,
                                             nullptr, nullptr, nullptr, nullptr, nullptr,
                                             nullptr, t2, N, invN);
    k_gather128b<<<nbG, 256, 0, stream>>>(t2, ecsr, rowptr, cur, dinv, b2, h2c, N);
    k_bn_stats_b<<<512, 256, 0, stream>>>(h2c, stats + 256, N);

    // final: [BN2ReLU(h2c) | relu(dist*Wd+bd) | relu(degf*Wg+bg)] @ Wm + bm -> d_out f32
    k_gemm<384, 2><<<nbGe, 256, 0, stream>>>((const unsigned short*)h2c, wmt, stats + 256,
                                             g2, be2, dist, degf, Wd, bd, Wg, bg,
                                             bm, d_out, N, invN);
}

// Round 8
// 472.891 us; speedup vs baseline: 12.5033x; 1.1156x over previous
//
#include <hip/hip_runtime.h>
#include <hip/hip_bf16.h>

#define BN_EPS 1e-5f

typedef __attribute__((ext_vector_type(8))) short bf16x8;
typedef __attribute__((ext_vector_type(4))) float f32x4;

__device__ __forceinline__ short f2b(float f) {
    __hip_bfloat16 h = __float2bfloat16(f);
    return *reinterpret_cast<short*>(&h);
}
__device__ __forceinline__ float bu2f(unsigned short u) {
    return __uint_as_float(((unsigned int)u) << 16);
}
__device__ __forceinline__ float lo16(unsigned int v) { return __uint_as_float(v << 16); }
__device__ __forceinline__ float hi16(unsigned int v) { return __uint_as_float(v & 0xffff0000u); }

#define DEG_SCALE 1048576.0f          /* 2^20 */
#define DEG_INV   (1.0f / 1048576.0f)
#define DEG_MASK  ((1ULL << 43) - 1)

// ---------------- int64-vs-int32 storage probe (one block) ----------------
__global__ void k_flag(const int* __restrict__ ei, int* __restrict__ flag) {
    __shared__ int any;
    if (threadIdx.x == 0) any = 0;
    __syncthreads();
    if (ei[2 * threadIdx.x + 1] != 0) atomicOr(&any, 1);
    __syncthreads();
    if (threadIdx.x == 0) *flag = (any == 0);  // all-high-words-zero => int64
}

// ---------------- histogram: packed {cnt|deg} per dst ----------------
__global__ void k_hist(const int* __restrict__ ei, const float* __restrict__ ew,
                       const int* __restrict__ flag, unsigned long long* __restrict__ packed,
                       int E) {
    int e = blockIdx.x * blockDim.x + threadIdx.x;
    if (e >= E) return;
    int d = (*flag) ? ei[2 * E + 2 * e] : ei[E + e];
    unsigned int wf = __float2uint_rn(ew[e] * DEG_SCALE);
    atomicAdd(&packed[d], (1ULL << 43) | (unsigned long long)wf);
}

// ---------------- scan stage 1 fused with unpack ----------------
__global__ void k_scan1(const unsigned long long* __restrict__ packed,
                        float* __restrict__ dinv, int* __restrict__ rowptr,
                        int* __restrict__ blktot, int N) {
    __shared__ int lds[256];
    int tid = threadIdx.x;
    int base = blockIdx.x * 1024 + tid * 4;
    int v[4]; int s = 0;
#pragma unroll
    for (int j = 0; j < 4; ++j) {
        int idx = base + j;
        if (idx < N) {
            unsigned long long p = packed[idx];
            v[j] = (int)(p >> 43);
            float deg = (float)(p & DEG_MASK) * DEG_INV;
            dinv[idx] = rsqrtf(deg + 1.0f);
        } else v[j] = 0;
        s += v[j];
    }
    lds[tid] = s;
    __syncthreads();
    for (int off = 1; off < 256; off <<= 1) {
        int t = (tid >= off) ? lds[tid - off] : 0;
        __syncthreads();
        lds[tid] += t;
        __syncthreads();
    }
    if (tid == 255) blktot[blockIdx.x] = lds[255];
    int run = lds[tid] - s;
#pragma unroll
    for (int j = 0; j < 4; ++j) {
        if (base + j < N) rowptr[base + j] = run;
        run += v[j];
    }
}

__global__ void k_scan2(int* blktot, int nb) {
    __shared__ int lds[256];
    int tid = threadIdx.x;
    int v = (tid < nb) ? blktot[tid] : 0;
    lds[tid] = v;
    __syncthreads();
    for (int off = 1; off < 256; off <<= 1) {
        int t = (tid >= off) ? lds[tid - off] : 0;
        __syncthreads();
        lds[tid] += t;
        __syncthreads();
    }
    if (tid < nb) blktot[tid] = lds[tid] - v;
}

__global__ void k_scan3(int* __restrict__ rowptr, const int* __restrict__ blktot,
                        int* __restrict__ cur, int N) {
    int i = blockIdx.x * blockDim.x + threadIdx.x;
    if (i < N) {
        int v = rowptr[i] + blktot[i >> 10];
        rowptr[i] = v;
        cur[i] = v;
    }
}

// ---------------- scatter edges into packed CSR ----------------
__global__ void k_scatter(const int* __restrict__ ei, const float* __restrict__ ew,
                          const int* __restrict__ flag, const float* __restrict__ dinv,
                          int* __restrict__ cur, int2* __restrict__ ecsr, int E) {
    int e = blockIdx.x * blockDim.x + threadIdx.x;
    if (e >= E) return;
    int s, d;
    if (*flag) { s = ei[2 * e]; d = ei[2 * E + 2 * e]; }
    else       { s = ei[e];     d = ei[E + e]; }
    int pos = atomicAdd(&cur[d], 1);
    int2 rec;
    rec.x = s;
    rec.y = __float_as_int(dinv[s] * ew[e] * dinv[d]);
    ecsr[pos] = rec;
}

// ---------------- weight transpose (bf16) + x -> bf16 table ----------------
__global__ void k_prep_wt(const float* __restrict__ W1, const float* __restrict__ W2,
                          const float* __restrict__ Wm, short* __restrict__ w1t,
                          short* __restrict__ w2t, short* __restrict__ wmt) {
    int idx = blockIdx.x * 256 + threadIdx.x;
    if (idx < 128 * 64) {
        int c = idx >> 6, k = idx & 63;
        w1t[idx] = f2b(W1[k * 128 + c]);
    } else if (idx < 128 * 64 + 128 * 128) {
        int i = idx - 128 * 64; int c = i >> 7, k = i & 127;
        w2t[i] = f2b(W2[k * 128 + c]);
    } else if (idx < 128 * 64 + 128 * 128 + 128 * 384) {
        int i = idx - (128 * 64 + 128 * 128); int c = i / 384, k = i % 384;
        wmt[i] = f2b(Wm[k * 128 + c]);
    }
}

__global__ void k_prep_xb(const float* __restrict__ x, unsigned short* __restrict__ xb,
                          int total4) {
    int i = blockIdx.x * blockDim.x + threadIdx.x;  // total4 = N*16
    if (i >= total4) return;
    float4 v = ((const float4*)x)[i];
    ushort4 o;
    o.x = (unsigned short)f2b(v.x);
    o.y = (unsigned short)f2b(v.y);
    o.z = (unsigned short)f2b(v.z);
    o.w = (unsigned short)f2b(v.w);
    ((ushort4*)xb)[i] = o;
}

// ---------------- MFMA GEMM (A always bf16) ----------------
// MODE 0: K=64  A=agg0[N][64];   out bf16 + bias eb (b1); fused BN-stats -> stats
// MODE 1: K=128 A=h1c[N][128] + BN(stats,g,be)+ReLU on load; out bf16, no bias
// MODE 2: K=384 virtual: k<128 BN2+ReLU(h2c bf16); 128..255 relu(dist*Wd+bd);
//         256..383 relu(degf*Wg+bg); out f32 + bias eb (bm)
template <int K, int MODE>
__global__ __launch_bounds__(256) void k_gemm(
        const unsigned short* __restrict__ A, const short* __restrict__ Bt,
        float* __restrict__ stats, const float* __restrict__ g,
        const float* __restrict__ be, const float* __restrict__ dist,
        const float* __restrict__ degf, const float* __restrict__ Wd,
        const float* __restrict__ bd, const float* __restrict__ Wg,
        const float* __restrict__ bg, const float* __restrict__ eb,
        void* __restrict__ out, int N, float invN) {
    __shared__ short As[64][48];
    __shared__ short Bs[128][48];
    __shared__ float sc[128], sh[128];
    __shared__ float st0[128], st1[128];
    const int t = threadIdx.x;
    const int lane = t & 63;
    const int wave = t >> 6;
    const int wr = wave >> 1, wc = wave & 1;
    const int r0 = blockIdx.x * 64;

    if (MODE >= 1) {
        if (t < 128) {
            float mean = stats[t] * invN;
            float var = stats[128 + t] * invN - mean * mean;
            float scale = g[t] * rsqrtf(var + BN_EPS);
            sc[t] = scale;
            sh[t] = be[t] - mean * scale;
        }
        __syncthreads();
    }
    if (MODE == 0) {
        if (t < 128) { st0[t] = 0.f; st1[t] = 0.f; }
        __syncthreads();
    }

    f32x4 acc[2][4];
#pragma unroll
    for (int m = 0; m < 2; ++m)
#pragma unroll
        for (int n = 0; n < 4; ++n) acc[m][n] = (f32x4){0.f, 0.f, 0.f, 0.f};

    for (int kt = 0; kt < K; kt += 32) {
        // ---- stage A ----
        {
            int r = t >> 2;
            int kk0 = (t & 3) * 8;
            int row = r0 + r;
            int kbase = kt + kk0;
            const int AST = (MODE == 0) ? 64 : 128;
            union { int4 q; unsigned short s[8]; } u;
            if (row < N) {
                if (MODE == 2 && kbase >= 128) {
                    const float* Wv; const float* bv; float sx; int cb;
                    if (kbase >= 256) { Wv = Wg; bv = bg; sx = degf[row]; cb = kbase - 256; }
                    else              { Wv = Wd; bv = bd; sx = dist[row]; cb = kbase - 128; }
#pragma unroll
                    for (int j = 0; j < 8; ++j)
                        u.s[j] = (unsigned short)f2b(fmaxf(0.f, sx * Wv[cb + j] + bv[cb + j]));
                } else if (MODE == 0) {
                    u.q = *(const int4*)(A + (size_t)row * AST + kbase);
                } else {
                    union { int4 q; unsigned short s[8]; } raw;
                    raw.q = *(const int4*)(A + (size_t)row * AST + kbase);
#pragma unroll
                    for (int j = 0; j < 8; ++j)
                        u.s[j] = (unsigned short)f2b(
                            fmaxf(0.f, bu2f(raw.s[j]) * sc[kbase + j] + sh[kbase + j]));
                }
            } else {
                u.q = (int4){0, 0, 0, 0};
            }
            *(int4*)&As[r][kk0] = u.q;
        }
        // ---- stage B ----
        {
            int c = t >> 1;
            const short* wrow = Bt + (size_t)c * K + kt;
            int half = t & 1;
            *(int4*)&Bs[c][half * 8]      = ((const int4*)wrow)[half];
            *(int4*)&Bs[c][half * 8 + 16] = ((const int4*)wrow)[half + 2];
        }
        __syncthreads();
        // ---- MFMA ----
        {
            const int g16 = (lane >> 4) * 8;
            const int rl = lane & 15;
            bf16x8 a0 = *reinterpret_cast<const bf16x8*>(&As[wr * 32 + rl][g16]);
            bf16x8 a1 = *reinterpret_cast<const bf16x8*>(&As[wr * 32 + 16 + rl][g16]);
#pragma unroll
            for (int n = 0; n < 4; ++n) {
                bf16x8 b = *reinterpret_cast<const bf16x8*>(&Bs[wc * 64 + n * 16 + rl][g16]);
                acc[0][n] = __builtin_amdgcn_mfma_f32_16x16x32_bf16(a0, b, acc[0][n], 0, 0, 0);
                acc[1][n] = __builtin_amdgcn_mfma_f32_16x16x32_bf16(a1, b, acc[1][n], 0, 0, 0);
            }
        }
        __syncthreads();
    }

    // ---- epilogue ----
    const int rbase = r0 + wr * 32 + (lane >> 4) * 4;
    const int cbase = wc * 64 + (lane & 15);
#pragma unroll
    for (int n = 0; n < 4; ++n) {
        int col = cbase + n * 16;
        float bias = (MODE != 1) ? eb[col] : 0.f;
        float sl = 0.f, ql = 0.f;
#pragma unroll
        for (int m = 0; m < 2; ++m) {
#pragma unroll
            for (int j = 0; j < 4; ++j) {
                int row = rbase + m * 16 + j;
                if (row < N) {
                    float val = acc[m][n][j] + bias;
                    if (MODE == 2) ((float*)out)[(size_t)row * 128 + col] = val;
                    else ((unsigned short*)out)[(size_t)row * 128 + col] = (unsigned short)f2b(val);
                    if (MODE == 0) { sl += val; ql += val * val; }
                }
            }
        }
        if (MODE == 0) {
            atomicAdd(&st0[col], sl);
            atomicAdd(&st1[col], ql);
        }
    }
    if (MODE == 0) {
        __syncthreads();
        if (t < 128) {
            atomicAdd(&stats[t], st0[t]);
            atomicAdd(&stats[128 + t], st1[t]);
        }
    }
}

// ---------------- CSR gathers (unroll x8) ----------------
__global__ void k_gather64(const unsigned short* __restrict__ xb, const int2* __restrict__ ecsr,
                           const int* __restrict__ rowptr, const int* __restrict__ rowend,
                           const float* __restrict__ dinv, unsigned short* __restrict__ agg0,
                           int N) {
    int node = blockIdx.x * 4 + (threadIdx.x >> 6);
    if (node >= N) return;
    int lane = threadIdx.x & 63;
    int start = rowptr[node], end = rowend[node];
    float di = dinv[node];
    float ax = di * di * bu2f(xb[(size_t)node * 64 + lane]);
    int j = start;
    for (; j + 8 <= end; j += 8) {
        float a0 = 0.f, a1 = 0.f;
#pragma unroll
        for (int u = 0; u < 8; u += 2) {
            int2 ea = ecsr[j + u], eb2 = ecsr[j + u + 1];
            a0 += __int_as_float(ea.y)  * bu2f(xb[(size_t)ea.x  * 64 + lane]);
            a1 += __int_as_float(eb2.y) * bu2f(xb[(size_t)eb2.x * 64 + lane]);
        }
        ax += a0 + a1;
    }
    for (; j < end; ++j) {
        int2 e = ecsr[j];
        ax += __int_as_float(e.y) * bu2f(xb[(size_t)e.x * 64 + lane]);
    }
    agg0[(size_t)node * 64 + lane] = (unsigned short)f2b(ax);
}

__global__ void k_gather128b(const unsigned int* __restrict__ t2, const int2* __restrict__ ecsr,
                             const int* __restrict__ rowptr, const int* __restrict__ rowend,
                             const float* __restrict__ dinv, const float* __restrict__ bias,
                             unsigned int* __restrict__ h2c, int N) {
    int node = blockIdx.x * 4 + (threadIdx.x >> 6);
    if (node >= N) return;
    int lane = threadIdx.x & 63;
    int start = rowptr[node], end = rowend[node];
    float di = dinv[node];
    float sl = di * di;
    unsigned int hv = t2[(size_t)node * 64 + lane];
    float2 bv = ((const float2*)bias)[lane];
    float ax = sl * lo16(hv) + bv.x;
    float ay = sl * hi16(hv) + bv.y;
    int j = start;
    for (; j + 8 <= end; j += 8) {
        int2 e[8]; unsigned int v[8];
#pragma unroll
        for (int u = 0; u < 8; ++u) e[u] = ecsr[j + u];
#pragma unroll
        for (int u = 0; u < 8; ++u) v[u] = t2[(size_t)e[u].x * 64 + lane];
#pragma unroll
        for (int u = 0; u < 8; ++u) {
            float w = __int_as_float(e[u].y);
            ax += w * lo16(v[u]);
            ay += w * hi16(v[u]);
        }
    }
    for (; j < end; ++j) {
        int2 e = ecsr[j];
        float w = __int_as_float(e.y);
        unsigned int v = t2[(size_t)e.x * 64 + lane];
        ax += w * lo16(v);
        ay += w * hi16(v);
    }
    unsigned int packed = (unsigned int)(unsigned short)f2b(ax) |
                          ((unsigned int)(unsigned short)f2b(ay) << 16);
    h2c[(size_t)node * 64 + lane] = packed;
}

// ---------------- BN2 stats: vectorized partials + final reduce ----------------
// h viewed as uint4 over N*64 uints; uint j holds channels 2*(j&63), 2*(j&63)+1.
__global__ __launch_bounds__(256) void k_bn_partial(const uint4* __restrict__ h,
                                                    float* __restrict__ part, int total4) {
    __shared__ float sm[256];  // [0:128) sum, [128:256) sumsq
    sm[threadIdx.x] = 0.f;
    __syncthreads();
    float s[8], q[8];
#pragma unroll
    for (int j = 0; j < 8; ++j) { s[j] = 0.f; q[j] = 0.f; }
    int stride = gridDim.x * 256;  // multiple of 16 -> channel group fixed per thread
    for (int i = blockIdx.x * 256 + threadIdx.x; i < total4; i += stride) {
        uint4 v = h[i];
        float a;
        a = lo16(v.x); s[0] += a; q[0] += a * a;
        a = hi16(v.x); s[1] += a; q[1] += a * a;
        a = lo16(v.y); s[2] += a; q[2] += a * a;
        a = hi16(v.y); s[3] += a; q[3] += a * a;
        a = lo16(v.z); s[4] += a; q[4] += a * a;
        a = hi16(v.z); s[5] += a; q[5] += a * a;
        a = lo16(v.w); s[6] += a; q[6] += a * a;
        a = hi16(v.w); s[7] += a; q[7] += a * a;
    }
    int c0 = 8 * (threadIdx.x & 15);  // channels c0..c0+7
#pragma unroll
    for (int j = 0; j < 8; ++j) {
        atomicAdd(&sm[c0 + j], s[j]);
        atomicAdd(&sm[128 + c0 + j], q[j]);
    }
    __syncthreads();
    part[blockIdx.x * 256 + threadIdx.x] = sm[threadIdx.x];
}

__global__ void k_bn_reduce(const float* __restrict__ part, float* __restrict__ stats, int nb) {
    int t = threadIdx.x;  // 256
    float acc = 0.f;
#pragma unroll 4
    for (int b = 0; b < nb; ++b) acc += part[b * 256 + t];
    stats[t] = acc;  // layout matches: [0:128) sum, [128:256) sumsq
}

extern "C" void kernel_launch(void* const* d_in, const int* in_sizes, int n_in,
                              void* d_out, int out_size, void* d_ws, size_t ws_size,
                              hipStream_t stream) {
    const float* x    = (const float*)d_in[0];
    const int*   ei   = (const int*)d_in[1];
    const float* ew   = (const float*)d_in[2];
    const float* dist = (const float*)d_in[3];
    const float* degf = (const float*)d_in[4];
    const float* W1   = (const float*)d_in[5];
    const float* b1   = (const float*)d_in[6];
    const float* W2   = (const float*)d_in[7];
    const float* b2   = (const float*)d_in[8];
    const float* g1   = (const float*)d_in[9];
    const float* be1  = (const float*)d_in[10];
    const float* g2   = (const float*)d_in[11];
    const float* be2  = (const float*)d_in[12];
    const float* Wd   = (const float*)d_in[13];
    const float* bd   = (const float*)d_in[14];
    const float* Wg   = (const float*)d_in[15];
    const float* bg   = (const float*)d_in[16];
    const float* Wm   = (const float*)d_in[17];
    const float* bm   = (const float*)d_in[18];

    const int IN = 64;
    const int N = in_sizes[0] / IN;   // 100000
    const int E = in_sizes[1] / 2;    // 1600000

    // ws layout (4B words):
    unsigned long long* packed = (unsigned long long*)d_ws;
    float* stats  = (float*)d_ws + 2 * (size_t)N;
    int*   flag   = (int*)(stats + 512);
    int*   rowptr = flag + 128;
    int*   cur    = rowptr + N;
    float* dinv   = (float*)(cur + N);
    int*   blktot = (int*)(dinv + N);
    int2*  ecsr   = (int2*)(blktot + 256);
    unsigned int*   h2c  = (unsigned int*)(ecsr + E);                // N*128 bf16
    unsigned short* agg0 = (unsigned short*)(h2c + (size_t)N * 64);  // N*64 bf16
    unsigned short* xb   = agg0 + (size_t)N * 64;                    // N*64 bf16
    short* w1t    = (short*)(xb + (size_t)N * 64);                   // [128][64]
    short* w2t    = w1t + 128 * 64;                                  // [128][128]
    short* wmt    = w2t + 128 * 128;                                 // [128][384]
    float* part   = (float*)(wmt + 128 * 384);                       // [512][256]

    // d_out time-share (bf16 staging, overwritten by final f32 GEMM)
    unsigned short* h1c = (unsigned short*)d_out;                    // N*128 bf16
    unsigned int*   t2  = (unsigned int*)d_out + (size_t)N * 64;     // N*128 bf16 pairs

    hipMemsetAsync(packed, 0, (2 * (size_t)N + 512) * sizeof(float), stream);

    const int nbE = (E + 255) / 256;
    const int nbN = (N + 255) / 256;
    const int nscan = (N + 1023) / 1024;

    k_flag<<<1, 256, 0, stream>>>(ei, flag);
    k_prep_wt<<<288, 256, 0, stream>>>(W1, W2, Wm, w1t, w2t, wmt);
    k_prep_xb<<<(N * 16 + 255) / 256, 256, 0, stream>>>(x, xb, N * 16);
    k_hist<<<nbE, 256, 0, stream>>>(ei, ew, flag, packed, E);
    k_scan1<<<nscan, 256, 0, stream>>>(packed, dinv, rowptr, blktot, N);
    k_scan2<<<1, 256, 0, stream>>>(blktot, nscan);
    k_scan3<<<nbN, 256, 0, stream>>>(rowptr, blktot, cur, N);
    k_scatter<<<nbE, 256, 0, stream>>>(ei, ew, flag, dinv, cur, ecsr, E);

    const int nbGe = (N + 63) / 64;
    const int nbG  = (N + 3) / 4;
    const int nbP  = 512;
    const float invN = 1.0f / (float)N;

    // layer 1: agg0 = A_hat @ x; h1c = agg0 @ W1 + b1 (stats1 fused in epilogue)
    k_gather64<<<nbG, 256, 0, stream>>>(xb, ecsr, rowptr, cur, dinv, agg0, N);
    k_gemm<64, 0><<<nbGe, 256, 0, stream>>>(agg0, w1t, stats, nullptr, nullptr, nullptr,
                                            nullptr, nullptr, nullptr, nullptr, nullptr,
                                            b1, h1c, N, invN);

    // layer 2: t2 = BN1ReLU(h1c) @ W2; h2c = A_hat @ t2 + b2; stats2 (two-stage)
    k_gemm<128, 1><<<nbGe, 256, 0, stream>>>(h1c, w2t, stats, g1, be1, nullptr,
                                             nullptr, nullptr, nullptr, nullptr, nullptr,
                                             nullptr, t2, N, invN);
    k_gather128b<<<nbG, 256, 0, stream>>>(t2, ecsr, rowptr, cur, dinv, b2, h2c, N);
    k_bn_partial<<<nbP, 256, 0, stream>>>((const uint4*)h2c, part, N * 16);
    k_bn_reduce<<<1, 256, 0, stream>>>(part, stats + 256, nbP);

    // final: [BN2ReLU(h2c) | relu(dist*Wd+bd) | relu(degf*Wg+bg)] @ Wm + bm -> d_out f32
    k_gemm<384, 2><<<nbGe, 256, 0, stream>>>((const unsigned short*)h2c, wmt, stats + 256,
                                             g2, be2, dist, degf, Wd, bd, Wg, bg,
                                             bm, d_out, N, invN);
}

// Round 9
// 471.057 us; speedup vs baseline: 12.5520x; 1.0039x over previous
//
#include <hip/hip_runtime.h>
#include <hip/hip_bf16.h>

#define BN_EPS 1e-5f

typedef __attribute__((ext_vector_type(8))) short bf16x8;
typedef __attribute__((ext_vector_type(4))) float f32x4;

__device__ __forceinline__ short f2b(float f) {
    __hip_bfloat16 h = __float2bfloat16(f);
    return *reinterpret_cast<short*>(&h);
}
__device__ __forceinline__ float bu2f(unsigned short u) {
    return __uint_as_float(((unsigned int)u) << 16);
}
__device__ __forceinline__ float lo16(unsigned int v) { return __uint_as_float(v << 16); }
__device__ __forceinline__ float hi16(unsigned int v) { return __uint_as_float(v & 0xffff0000u); }

#define DEG_SCALE 1048576.0f          /* 2^20 */
#define DEG_INV   (1.0f / 1048576.0f)
#define DEG_MASK  ((1ULL << 43) - 1)

// ---------------- int64-vs-int32 storage probe (one block) ----------------
__global__ void k_flag(const int* __restrict__ ei, int* __restrict__ flag) {
    __shared__ int any;
    if (threadIdx.x == 0) any = 0;
    __syncthreads();
    if (ei[2 * threadIdx.x + 1] != 0) atomicOr(&any, 1);
    __syncthreads();
    if (threadIdx.x == 0) *flag = (any == 0);  // all-high-words-zero => int64
}

// ---------------- histogram into 8 slot-local copies (XCD-local atomics) ----------------
// packed8[slot][d] accumulates {cnt:21 | deg*2^20:43}; slot = blockIdx&7 (~XCD id under
// round-robin dispatch; correctness independent of mapping).
__global__ void k_hist8(const int* __restrict__ ei, const float* __restrict__ ew,
                        const int* __restrict__ flag,
                        unsigned long long* __restrict__ packed8, int E, int N) {
    int e = blockIdx.x * blockDim.x + threadIdx.x;
    if (e >= E) return;
    int slot = blockIdx.x & 7;
    int d = (*flag) ? ei[2 * E + 2 * e] : ei[E + e];
    unsigned int wf = __float2uint_rn(ew[e] * DEG_SCALE);
    atomicAdd(&packed8[(size_t)slot * N + d], (1ULL << 43) | (unsigned long long)wf);
}

// ---------------- scan stage 1 fused with 8-copy merge + unpack ----------------
__global__ void k_scan1(const unsigned long long* __restrict__ packed8,
                        float* __restrict__ dinv, int* __restrict__ rowptr,
                        int* __restrict__ blktot, int N) {
    __shared__ int lds[256];
    int tid = threadIdx.x;
    int base = blockIdx.x * 1024 + tid * 4;
    int v[4]; int s = 0;
#pragma unroll
    for (int j = 0; j < 4; ++j) {
        int idx = base + j;
        if (idx < N) {
            unsigned long long ctot = 0, dtot = 0;
#pragma unroll
            for (int cpy = 0; cpy < 8; ++cpy) {
                unsigned long long p = packed8[(size_t)cpy * N + idx];
                ctot += p >> 43;
                dtot += p & DEG_MASK;
            }
            v[j] = (int)ctot;
            float deg = (float)dtot * DEG_INV;
            dinv[idx] = rsqrtf(deg + 1.0f);
        } else v[j] = 0;
        s += v[j];
    }
    lds[tid] = s;
    __syncthreads();
    for (int off = 1; off < 256; off <<= 1) {
        int t = (tid >= off) ? lds[tid - off] : 0;
        __syncthreads();
        lds[tid] += t;
        __syncthreads();
    }
    if (tid == 255) blktot[blockIdx.x] = lds[255];
    int run = lds[tid] - s;
#pragma unroll
    for (int j = 0; j < 4; ++j) {
        if (base + j < N) rowptr[base + j] = run;
        run += v[j];
    }
}

__global__ void k_scan2(int* blktot, int nb) {
    __shared__ int lds[256];
    int tid = threadIdx.x;
    int v = (tid < nb) ? blktot[tid] : 0;
    lds[tid] = v;
    __syncthreads();
    for (int off = 1; off < 256; off <<= 1) {
        int t = (tid >= off) ? lds[tid - off] : 0;
        __syncthreads();
        lds[tid] += t;
        __syncthreads();
    }
    if (tid < nb) blktot[tid] = lds[tid] - v;
}

__global__ void k_scan3(int* __restrict__ rowptr, const int* __restrict__ blktot,
                        int* __restrict__ cur, int N) {
    int i = blockIdx.x * blockDim.x + threadIdx.x;
    if (i < N) {
        int v = rowptr[i] + blktot[i >> 10];
        rowptr[i] = v;
        cur[i] = v;
    }
}

// ---------------- slot-chunked scatter: block (chunk, slot) writes only slot's dst range ----
// All ecsr/cur traffic for a dst range comes from one slot (~one XCD) -> lines merge
// in local L2 instead of bouncing cross-XCD. Costs 8x dst reads (L3-resident).
__global__ void k_scatter(const int* __restrict__ ei, const float* __restrict__ ew,
                          const int* __restrict__ flag, const float* __restrict__ dinv,
                          int* __restrict__ cur, int2* __restrict__ ecsr, int E, int N) {
    int slot = blockIdx.x & 7;
    int chunk = blockIdx.x >> 3;
    int e = chunk * 256 + threadIdx.x;
    if (e >= E) return;
    int d = (*flag) ? ei[2 * E + 2 * e] : ei[E + e];
    int N8 = (N + 7) >> 3;
    int lo = slot * N8;
    if (d < lo || d >= lo + N8) return;
    int s = (*flag) ? ei[2 * e] : ei[e];
    int pos = atomicAdd(&cur[d], 1);
    int2 rec;
    rec.x = s;
    rec.y = __float_as_int(dinv[s] * ew[e] * dinv[d]);
    ecsr[pos] = rec;
}

// ---------------- weight transpose (bf16) + x -> bf16 table ----------------
__global__ void k_prep_wt(const float* __restrict__ W1, const float* __restrict__ W2,
                          const float* __restrict__ Wm, short* __restrict__ w1t,
                          short* __restrict__ w2t, short* __restrict__ wmt) {
    int idx = blockIdx.x * 256 + threadIdx.x;
    if (idx < 128 * 64) {
        int c = idx >> 6, k = idx & 63;
        w1t[idx] = f2b(W1[k * 128 + c]);
    } else if (idx < 128 * 64 + 128 * 128) {
        int i = idx - 128 * 64; int c = i >> 7, k = i & 127;
        w2t[i] = f2b(W2[k * 128 + c]);
    } else if (idx < 128 * 64 + 128 * 128 + 128 * 384) {
        int i = idx - (128 * 64 + 128 * 128); int c = i / 384, k = i % 384;
        wmt[i] = f2b(Wm[k * 128 + c]);
    }
}

__global__ void k_prep_xb(const float* __restrict__ x, unsigned short* __restrict__ xb,
                          int total4) {
    int i = blockIdx.x * blockDim.x + threadIdx.x;  // total4 = N*16
    if (i >= total4) return;
    float4 v = ((const float4*)x)[i];
    ushort4 o;
    o.x = (unsigned short)f2b(v.x);
    o.y = (unsigned short)f2b(v.y);
    o.z = (unsigned short)f2b(v.z);
    o.w = (unsigned short)f2b(v.w);
    ((ushort4*)xb)[i] = o;
}

// ---------------- MFMA GEMM (A always bf16) ----------------
// MODE 0: K=64  A=agg0[N][64];   out bf16 + bias eb (b1); fused BN-stats -> stats
// MODE 1: K=128 A=h1c[N][128] + BN(stats,g,be)+ReLU on load; out bf16, no bias
// MODE 2: K=384 virtual: k<128 BN2+ReLU(h2c bf16); 128..255 relu(dist*Wd+bd);
//         256..383 relu(degf*Wg+bg); out f32 + bias eb (bm)
template <int K, int MODE>
__global__ __launch_bounds__(256) void k_gemm(
        const unsigned short* __restrict__ A, const short* __restrict__ Bt,
        float* __restrict__ stats, const float* __restrict__ g,
        const float* __restrict__ be, const float* __restrict__ dist,
        const float* __restrict__ degf, const float* __restrict__ Wd,
        const float* __restrict__ bd, const float* __restrict__ Wg,
        const float* __restrict__ bg, const float* __restrict__ eb,
        void* __restrict__ out, int N, float invN) {
    __shared__ short As[64][48];
    __shared__ short Bs[128][48];
    __shared__ float sc[128], sh[128];
    __shared__ float st0[128], st1[128];
    const int t = threadIdx.x;
    const int lane = t & 63;
    const int wave = t >> 6;
    const int wr = wave >> 1, wc = wave & 1;
    const int r0 = blockIdx.x * 64;

    if (MODE >= 1) {
        if (t < 128) {
            float mean = stats[t] * invN;
            float var = stats[128 + t] * invN - mean * mean;
            float scale = g[t] * rsqrtf(var + BN_EPS);
            sc[t] = scale;
            sh[t] = be[t] - mean * scale;
        }
        __syncthreads();
    }
    if (MODE == 0) {
        if (t < 128) { st0[t] = 0.f; st1[t] = 0.f; }
        __syncthreads();
    }

    f32x4 acc[2][4];
#pragma unroll
    for (int m = 0; m < 2; ++m)
#pragma unroll
        for (int n = 0; n < 4; ++n) acc[m][n] = (f32x4){0.f, 0.f, 0.f, 0.f};

    for (int kt = 0; kt < K; kt += 32) {
        // ---- stage A ----
        {
            int r = t >> 2;
            int kk0 = (t & 3) * 8;
            int row = r0 + r;
            int kbase = kt + kk0;
            const int AST = (MODE == 0) ? 64 : 128;
            union { int4 q; unsigned short s[8]; } u;
            if (row < N) {
                if (MODE == 2 && kbase >= 128) {
                    const float* Wv; const float* bv; float sx; int cb;
                    if (kbase >= 256) { Wv = Wg; bv = bg; sx = degf[row]; cb = kbase - 256; }
                    else              { Wv = Wd; bv = bd; sx = dist[row]; cb = kbase - 128; }
#pragma unroll
                    for (int j = 0; j < 8; ++j)
                        u.s[j] = (unsigned short)f2b(fmaxf(0.f, sx * Wv[cb + j] + bv[cb + j]));
                } else if (MODE == 0) {
                    u.q = *(const int4*)(A + (size_t)row * AST + kbase);
                } else {
                    union { int4 q; unsigned short s[8]; } raw;
                    raw.q = *(const int4*)(A + (size_t)row * AST + kbase);
#pragma unroll
                    for (int j = 0; j < 8; ++j)
                        u.s[j] = (unsigned short)f2b(
                            fmaxf(0.f, bu2f(raw.s[j]) * sc[kbase + j] + sh[kbase + j]));
                }
            } else {
                u.q = (int4){0, 0, 0, 0};
            }
            *(int4*)&As[r][kk0] = u.q;
        }
        // ---- stage B ----
        {
            int c = t >> 1;
            const short* wrow = Bt + (size_t)c * K + kt;
            int half = t & 1;
            *(int4*)&Bs[c][half * 8]      = ((const int4*)wrow)[half];
            *(int4*)&Bs[c][half * 8 + 16] = ((const int4*)wrow)[half + 2];
        }
        __syncthreads();
        // ---- MFMA ----
        {
            const int g16 = (lane >> 4) * 8;
            const int rl = lane & 15;
            bf16x8 a0 = *reinterpret_cast<const bf16x8*>(&As[wr * 32 + rl][g16]);
            bf16x8 a1 = *reinterpret_cast<const bf16x8*>(&As[wr * 32 + 16 + rl][g16]);
#pragma unroll
            for (int n = 0; n < 4; ++n) {
                bf16x8 b = *reinterpret_cast<const bf16x8*>(&Bs[wc * 64 + n * 16 + rl][g16]);
                acc[0][n] = __builtin_amdgcn_mfma_f32_16x16x32_bf16(a0, b, acc[0][n], 0, 0, 0);
                acc[1][n] = __builtin_amdgcn_mfma_f32_16x16x32_bf16(a1, b, acc[1][n], 0, 0, 0);
            }
        }
        __syncthreads();
    }

    // ---- epilogue ----
    const int rbase = r0 + wr * 32 + (lane >> 4) * 4;
    const int cbase = wc * 64 + (lane & 15);
#pragma unroll
    for (int n = 0; n < 4; ++n) {
        int col = cbase + n * 16;
        float bias = (MODE != 1) ? eb[col] : 0.f;
        float sl = 0.f, ql = 0.f;
#pragma unroll
        for (int m = 0; m < 2; ++m) {
#pragma unroll
            for (int j = 0; j < 4; ++j) {
                int row = rbase + m * 16 + j;
                if (row < N) {
                    float val = acc[m][n][j] + bias;
                    if (MODE == 2) ((float*)out)[(size_t)row * 128 + col] = val;
                    else ((unsigned short*)out)[(size_t)row * 128 + col] = (unsigned short)f2b(val);
                    if (MODE == 0) { sl += val; ql += val * val; }
                }
            }
        }
        if (MODE == 0) {
            atomicAdd(&st0[col], sl);
            atomicAdd(&st1[col], ql);
        }
    }
    if (MODE == 0) {
        __syncthreads();
        if (t < 128) {
            atomicAdd(&stats[t], st0[t]);
            atomicAdd(&stats[128 + t], st1[t]);
        }
    }
}

// ---------------- CSR gathers (unroll x8) ----------------
__global__ void k_gather64(const unsigned short* __restrict__ xb, const int2* __restrict__ ecsr,
                           const int* __restrict__ rowptr, const int* __restrict__ rowend,
                           const float* __restrict__ dinv, unsigned short* __restrict__ agg0,
                           int N) {
    int node = blockIdx.x * 4 + (threadIdx.x >> 6);
    if (node >= N) return;
    int lane = threadIdx.x & 63;
    int start = rowptr[node], end = rowend[node];
    float di = dinv[node];
    float ax = di * di * bu2f(xb[(size_t)node * 64 + lane]);
    int j = start;
    for (; j + 8 <= end; j += 8) {
        float a0 = 0.f, a1 = 0.f;
#pragma unroll
        for (int u = 0; u < 8; u += 2) {
            int2 ea = ecsr[j + u], eb2 = ecsr[j + u + 1];
            a0 += __int_as_float(ea.y)  * bu2f(xb[(size_t)ea.x  * 64 + lane]);
            a1 += __int_as_float(eb2.y) * bu2f(xb[(size_t)eb2.x * 64 + lane]);
        }
        ax += a0 + a1;
    }
    for (; j < end; ++j) {
        int2 e = ecsr[j];
        ax += __int_as_float(e.y) * bu2f(xb[(size_t)e.x * 64 + lane]);
    }
    agg0[(size_t)node * 64 + lane] = (unsigned short)f2b(ax);
}

__global__ void k_gather128b(const unsigned int* __restrict__ t2, const int2* __restrict__ ecsr,
                             const int* __restrict__ rowptr, const int* __restrict__ rowend,
                             const float* __restrict__ dinv, const float* __restrict__ bias,
                             unsigned int* __restrict__ h2c, int N) {
    int node = blockIdx.x * 4 + (threadIdx.x >> 6);
    if (node >= N) return;
    int lane = threadIdx.x & 63;
    int start = rowptr[node], end = rowend[node];
    float di = dinv[node];
    float sl = di * di;
    unsigned int hv = t2[(size_t)node * 64 + lane];
    float2 bv = ((const float2*)bias)[lane];
    float ax = sl * lo16(hv) + bv.x;
    float ay = sl * hi16(hv) + bv.y;
    int j = start;
    for (; j + 8 <= end; j += 8) {
        int2 e[8]; unsigned int v[8];
#pragma unroll
        for (int u = 0; u < 8; ++u) e[u] = ecsr[j + u];
#pragma unroll
        for (int u = 0; u < 8; ++u) v[u] = t2[(size_t)e[u].x * 64 + lane];
#pragma unroll
        for (int u = 0; u < 8; ++u) {
            float w = __int_as_float(e[u].y);
            ax += w * lo16(v[u]);
            ay += w * hi16(v[u]);
        }
    }
    for (; j < end; ++j) {
        int2 e = ecsr[j];
        float w = __int_as_float(e.y);
        unsigned int v = t2[(size_t)e.x * 64 + lane];
        ax += w * lo16(v);
        ay += w * hi16(v);
    }
    unsigned int packed = (unsigned int)(unsigned short)f2b(ax) |
                          ((unsigned int)(unsigned short)f2b(ay) << 16);
    h2c[(size_t)node * 64 + lane] = packed;
}

// ---------------- BN2 stats: vectorized partials + final reduce ----------------
__global__ __launch_bounds__(256) void k_bn_partial(const uint4* __restrict__ h,
                                                    float* __restrict__ part, int total4) {
    __shared__ float sm[256];
    sm[threadIdx.x] = 0.f;
    __syncthreads();
    float s[8], q[8];
#pragma unroll
    for (int j = 0; j < 8; ++j) { s[j] = 0.f; q[j] = 0.f; }
    int stride = gridDim.x * 256;
    for (int i = blockIdx.x * 256 + threadIdx.x; i < total4; i += stride) {
        uint4 v = h[i];
        float a;
        a = lo16(v.x); s[0] += a; q[0] += a * a;
        a = hi16(v.x); s[1] += a; q[1] += a * a;
        a = lo16(v.y); s[2] += a; q[2] += a * a;
        a = hi16(v.y); s[3] += a; q[3] += a * a;
        a = lo16(v.z); s[4] += a; q[4] += a * a;
        a = hi16(v.z); s[5] += a; q[5] += a * a;
        a = lo16(v.w); s[6] += a; q[6] += a * a;
        a = hi16(v.w); s[7] += a; q[7] += a * a;
    }
    int c0 = 8 * (threadIdx.x & 15);
#pragma unroll
    for (int j = 0; j < 8; ++j) {
        atomicAdd(&sm[c0 + j], s[j]);
        atomicAdd(&sm[128 + c0 + j], q[j]);
    }
    __syncthreads();
    part[blockIdx.x * 256 + threadIdx.x] = sm[threadIdx.x];
}

__global__ void k_bn_reduce(const float* __restrict__ part, float* __restrict__ stats, int nb) {
    int t = threadIdx.x;
    float acc = 0.f;
#pragma unroll 4
    for (int b = 0; b < nb; ++b) acc += part[b * 256 + t];
    stats[t] = acc;
}

extern "C" void kernel_launch(void* const* d_in, const int* in_sizes, int n_in,
                              void* d_out, int out_size, void* d_ws, size_t ws_size,
                              hipStream_t stream) {
    const float* x    = (const float*)d_in[0];
    const int*   ei   = (const int*)d_in[1];
    const float* ew   = (const float*)d_in[2];
    const float* dist = (const float*)d_in[3];
    const float* degf = (const float*)d_in[4];
    const float* W1   = (const float*)d_in[5];
    const float* b1   = (const float*)d_in[6];
    const float* W2   = (const float*)d_in[7];
    const float* b2   = (const float*)d_in[8];
    const float* g1   = (const float*)d_in[9];
    const float* be1  = (const float*)d_in[10];
    const float* g2   = (const float*)d_in[11];
    const float* be2  = (const float*)d_in[12];
    const float* Wd   = (const float*)d_in[13];
    const float* bd   = (const float*)d_in[14];
    const float* Wg   = (const float*)d_in[15];
    const float* bg   = (const float*)d_in[16];
    const float* Wm   = (const float*)d_in[17];
    const float* bm   = (const float*)d_in[18];

    const int IN = 64;
    const int N = in_sizes[0] / IN;   // 100000
    const int E = in_sizes[1] / 2;    // 1600000

    // ws layout (4B words):
    unsigned long long* packed8 = (unsigned long long*)d_ws;         // [8][N] u64
    float* stats  = (float*)d_ws + 16 * (size_t)N;
    int*   flag   = (int*)(stats + 512);
    int*   rowptr = flag + 128;
    int*   cur    = rowptr + N;
    float* dinv   = (float*)(cur + N);
    int*   blktot = (int*)(dinv + N);
    int2*  ecsr   = (int2*)(blktot + 256);
    unsigned int*   h2c  = (unsigned int*)(ecsr + E);                // N*128 bf16
    unsigned short* agg0 = (unsigned short*)(h2c + (size_t)N * 64);  // N*64 bf16
    unsigned short* xb   = agg0 + (size_t)N * 64;                    // N*64 bf16
    short* w1t    = (short*)(xb + (size_t)N * 64);                   // [128][64]
    short* w2t    = w1t + 128 * 64;                                  // [128][128]
    short* wmt    = w2t + 128 * 128;                                 // [128][384]
    float* part   = (float*)(wmt + 128 * 384);                       // [512][256]

    // d_out time-share (bf16 staging, overwritten by final f32 GEMM)
    unsigned short* h1c = (unsigned short*)d_out;                    // N*128 bf16
    unsigned int*   t2  = (unsigned int*)d_out + (size_t)N * 64;     // N*128 bf16 pairs

    hipMemsetAsync(packed8, 0, (16 * (size_t)N + 512) * sizeof(float), stream);

    const int nbE = (E + 255) / 256;
    const int nbN = (N + 255) / 256;
    const int nscan = (N + 1023) / 1024;

    k_flag<<<1, 256, 0, stream>>>(ei, flag);
    k_prep_wt<<<288, 256, 0, stream>>>(W1, W2, Wm, w1t, w2t, wmt);
    k_prep_xb<<<(N * 16 + 255) / 256, 256, 0, stream>>>(x, xb, N * 16);
    k_hist8<<<nbE, 256, 0, stream>>>(ei, ew, flag, packed8, E, N);
    k_scan1<<<nscan, 256, 0, stream>>>(packed8, dinv, rowptr, blktot, N);
    k_scan2<<<1, 256, 0, stream>>>(blktot, nscan);
    k_scan3<<<nbN, 256, 0, stream>>>(rowptr, blktot, cur, N);
    k_scatter<<<nbE * 8, 256, 0, stream>>>(ei, ew, flag, dinv, cur, ecsr, E, N);

    const int nbGe = (N + 63) / 64;
    const int nbG  = (N + 3) / 4;
    const int nbP  = 512;
    const float invN = 1.0f / (float)N;

    // layer 1: agg0 = A_hat @ x; h1c = agg0 @ W1 + b1 (stats1 fused in epilogue)
    k_gather64<<<nbG, 256, 0, stream>>>(xb, ecsr, rowptr, cur, dinv, agg0, N);
    k_gemm<64, 0><<<nbGe, 256, 0, stream>>>(agg0, w1t, stats, nullptr, nullptr, nullptr,
                                            nullptr, nullptr, nullptr, nullptr, nullptr,
                                            b1, h1c, N, invN);

    // layer 2: t2 = BN1ReLU(h1c) @ W2; h2c = A_hat @ t2 + b2; stats2 (two-stage)
    k_gemm<128, 1><<<nbGe, 256, 0, stream>>>(h1c, w2t, stats, g1, be1, nullptr,
                                             nullptr, nullptr, nullptr, nullptr, nullptr,
                                             nullptr, t2, N, invN);
    k_gather128b<<<nbG, 256, 0, stream>>>(t2, ecsr, rowptr, cur, dinv, b2, h2c, N);
    k_bn_partial<<<nbP, 256, 0, stream>>>((const uint4*)h2c, part, N * 16);
    k_bn_reduce<<<1, 256, 0, stream>>>(part, stats + 256, nbP);

    // final: [BN2ReLU(h2c) | relu(dist*Wd+bd) | relu(degf*Wg+bg)] @ Wm + bm -> d_out f32
    k_gemm<384, 2><<<nbGe, 256, 0, stream>>>((const unsigned short*)h2c, wmt, stats + 256,
                                             g2, be2, dist, degf, Wd, bd, Wg, bg,
                                             bm, d_out, N, invN);
}